// Round 1
// baseline (355.023 us; speedup 1.0000x reference)
//
#include <hip/hip_runtime.h>
#include <hip/hip_bf16.h>

#define BB 8
#define SS 128
#define HID 768
#define DEP 64
#define DSZ 768
#define NT 45
#define NEG -1000000000.0f

// ---------------------------------------------------------------------------
// E1[t,e] = sum_d table[t,d] * W1[(HID+d), e]   (and E2 with W2)
__global__ void e_kernel(const float* __restrict__ table,
                         const float* __restrict__ W1,
                         const float* __restrict__ W2,
                         float* __restrict__ E1, float* __restrict__ E2) {
    int idx = blockIdx.x * blockDim.x + threadIdx.x;
    if (idx >= NT * DSZ) return;
    int t = idx / DSZ, e = idx % DSZ;
    float s1 = 0.f, s2 = 0.f;
    for (int d = 0; d < DEP; ++d) {
        float td = table[t * DEP + d];
        s1 += td * W1[(HID + d) * DSZ + e];
        s2 += td * W2[(HID + d) * DSZ + e];
    }
    E1[idx] = s1;
    E2[idx] = s2;
}

// c[t] = dot(E1[t,:], E2[t,:])
__global__ void c_kernel(const float* __restrict__ E1, const float* __restrict__ E2,
                         float* __restrict__ cv) {
    int t = blockIdx.x;
    float s = 0.f;
    for (int e = threadIdx.x; e < DSZ; e += 256)
        s += E1[t * DSZ + e] * E2[t * DSZ + e];
    __shared__ float red[256];
    red[threadIdx.x] = s;
    __syncthreads();
    for (int w = 128; w >= 1; w >>= 1) {
        if (threadIdx.x < w) red[threadIdx.x] += red[threadIdx.x + w];
        __syncthreads();
    }
    if (threadIdx.x == 0) cv[t] = red[0];
}

// ---------------------------------------------------------------------------
// Generic tiled fp32 GEMM: C = A @ B + bias, optional relu, batched strided.
// Tile 64x64, Kc=16, 256 threads, each thread 4x4 outputs.
// Grid: (N/64, Mb/64, batch)
template <bool RELU>
__global__ __launch_bounds__(256) void gemm_bias(
    const float* __restrict__ A, const float* __restrict__ Bm,
    const float* __restrict__ bias, float* __restrict__ C,
    int K, int lda, int ldb, int ldc,
    long strideA, long strideB, long strideC) {
    __shared__ float As[16][64 + 1];  // [kk][m]
    __shared__ float Bs[16][64 + 1];  // [kk][n]
    const float* Ab = A + (long)blockIdx.z * strideA;
    const float* Bb = Bm + (long)blockIdx.z * strideB;
    float* Cb = C + (long)blockIdx.z * strideC;
    int tx = threadIdx.x % 16, ty = threadIdx.x / 16;
    int row0 = blockIdx.y * 64, col0 = blockIdx.x * 64;
    float acc[4][4] = {};
    for (int k0 = 0; k0 < K; k0 += 16) {
        for (int l = 0; l < 4; ++l) {
            int idx = threadIdx.x + l * 256;  // 0..1023
            int r = idx / 16, kk = idx % 16;
            As[kk][r] = Ab[(row0 + r) * lda + k0 + kk];
            int kk2 = idx / 64, cc = idx % 64;
            Bs[kk2][cc] = Bb[(k0 + kk2) * ldb + col0 + cc];
        }
        __syncthreads();
        for (int kk = 0; kk < 16; ++kk) {
            float a[4], b[4];
            for (int i = 0; i < 4; ++i) a[i] = As[kk][ty * 4 + i];
            for (int j = 0; j < 4; ++j) b[j] = Bs[kk][tx * 4 + j];
            for (int i = 0; i < 4; ++i)
                for (int j = 0; j < 4; ++j) acc[i][j] += a[i] * b[j];
        }
        __syncthreads();
    }
    for (int i = 0; i < 4; ++i)
        for (int j = 0; j < 4; ++j) {
            int r = row0 + ty * 4 + i, cc = col0 + tx * 4 + j;
            float v = acc[i][j] + (bias ? bias[cc] : 0.f);
            if (RELU) v = fmaxf(v, 0.f);
            Cb[r * ldc + cc] = v;
        }
}

// ---------------------------------------------------------------------------
// G[b,i,j] = dot(P1[b,i,:], P2[b,j,:])  -- batched Gram, K=768
// Tile 32x32, Kc=32, 256 threads, each thread 4 i-rows x 1 j-col.
// Grid: (S/32, S/32, B)
__global__ __launch_bounds__(256) void gram_kernel(
    const float* __restrict__ P1, const float* __restrict__ P2,
    float* __restrict__ G) {
    int b = blockIdx.z;
    int i0 = blockIdx.y * 32, j0 = blockIdx.x * 32;
    __shared__ float As[32][32 + 1];  // [kk][i]
    __shared__ float Bs[32][32 + 1];  // [kk][j]
    const float* p1 = P1 + (long)b * SS * DSZ;
    const float* p2 = P2 + (long)b * SS * DSZ;
    int tx = threadIdx.x % 32, ty = threadIdx.x / 32;  // ty 0..7
    float acc[4] = {0.f, 0.f, 0.f, 0.f};
    for (int k0 = 0; k0 < DSZ; k0 += 32) {
        for (int l = 0; l < 4; ++l) {
            int idx = threadIdx.x + l * 256;
            int r = idx / 32, kk = idx % 32;
            As[kk][r] = p1[(i0 + r) * DSZ + k0 + kk];
            Bs[kk][r] = p2[(j0 + r) * DSZ + k0 + kk];
        }
        __syncthreads();
        for (int kk = 0; kk < 32; ++kk) {
            float bv = Bs[kk][tx];
            for (int i = 0; i < 4; ++i) acc[i] += As[kk][ty * 4 + i] * bv;
        }
        __syncthreads();
    }
    for (int i = 0; i < 4; ++i)
        G[((long)b * SS + i0 + ty * 4 + i) * SS + j0 + tx] = acc[i];
}

// ---------------------------------------------------------------------------
// U[bs,t] = dot(P1[bs,:], E2[t,:]);  V[bs,t] = dot(P2[bs,:], E1[t,:]) + c[t]
// One block per (b,s); 4 waves, wave-strided over t.
__global__ __launch_bounds__(256) void uv_kernel(
    const float* __restrict__ P1, const float* __restrict__ P2,
    const float* __restrict__ E1, const float* __restrict__ E2,
    const float* __restrict__ cv, float* __restrict__ U, float* __restrict__ V) {
    int bs = blockIdx.x;
    __shared__ float p1[DSZ], p2[DSZ];
    for (int e = threadIdx.x; e < DSZ; e += 256) {
        p1[e] = P1[(long)bs * DSZ + e];
        p2[e] = P2[(long)bs * DSZ + e];
    }
    __syncthreads();
    int wave = threadIdx.x / 64, lane = threadIdx.x % 64;
    for (int t = wave; t < NT; t += 4) {
        float su = 0.f, sv = 0.f;
        for (int e = lane; e < DSZ; e += 64) {
            su += p1[e] * E2[t * DSZ + e];
            sv += p2[e] * E1[t * DSZ + e];
        }
        for (int off = 32; off >= 1; off >>= 1) {
            su += __shfl_down(su, off);
            sv += __shfl_down(sv, off);
        }
        if (lane == 0) {
            U[(long)bs * NT + t] = su;
            V[(long)bs * NT + t] = sv + cv[t];
        }
    }
}

// ---------------------------------------------------------------------------
// relevance + mask + softmax over j.  One block per (b,i), 128 threads.
__global__ __launch_bounds__(128) void softmax_kernel(
    const int* __restrict__ dep, const float* __restrict__ G,
    const float* __restrict__ U, const float* __restrict__ V,
    float* __restrict__ A) {
    int bi = blockIdx.x;  // b*S + i
    int b = bi / SS;
    int j = threadIdx.x;
    int t = dep[(long)bi * SS + j];
    float r;
    if (t != 0)
        r = G[(long)bi * SS + j] + U[(long)bi * NT + t] + V[((long)b * SS + j) * NT + t];
    else
        r = NEG;
    float m = r;
    for (int off = 1; off < 64; off <<= 1) m = fmaxf(m, __shfl_xor(m, off));
    __shared__ float smax[2], ssum[2];
    if ((threadIdx.x & 63) == 0) smax[threadIdx.x >> 6] = m;
    __syncthreads();
    m = fmaxf(smax[0], smax[1]);
    float p = expf(r - m);
    float s = p;
    for (int off = 1; off < 64; off <<= 1) s += __shfl_xor(s, off);
    if ((threadIdx.x & 63) == 0) ssum[threadIdx.x >> 6] = s;
    __syncthreads();
    s = ssum[0] + ssum[1];
    A[(long)bi * SS + j] = p / s;
}

// ---------------------------------------------------------------------------
extern "C" void kernel_launch(void* const* d_in, const int* in_sizes, int n_in,
                              void* d_out, int out_size, void* d_ws, size_t ws_size,
                              hipStream_t stream) {
    const float* h      = (const float*)d_in[0];
    const int*   dep    = (const int*)d_in[1];
    const float* table  = (const float*)d_in[2];
    const float* W1_w   = (const float*)d_in[3];
    const float* W1_b   = (const float*)d_in[4];
    const float* W2_w   = (const float*)d_in[5];
    const float* W2_b   = (const float*)d_in[6];
    const float* gcn_w  = (const float*)d_in[7];
    const float* gcn_b  = (const float*)d_in[8];
    const float* Wo_w   = (const float*)d_in[9];
    const float* Wo_b   = (const float*)d_in[10];
    float* out = (float*)d_out;

    float* ws = (float*)d_ws;
    const long nBS = (long)BB * SS;           // 1024
    float* P1   = ws;                          // 1024*768
    float* P2   = P1 + nBS * DSZ;              // 1024*768
    float* E1   = P2 + nBS * DSZ;              // 45*768
    float* E2   = E1 + NT * DSZ;               // 45*768
    float* CV   = E2 + NT * DSZ;               // 64 (45 used)
    float* U    = CV + 64;                     // 1024*45
    float* V    = U + nBS * NT;                // 1024*45
    float* G    = V + nBS * NT;                // 8*128*128
    float* Amat = G + (long)BB * SS * SS;      // 8*128*128
    float* AGG  = Amat + (long)BB * SS * SS;   // 1024*768
    float* HSYN = AGG + nBS * DSZ;             // 1024*768

    // 1. E1/E2
    e_kernel<<<(NT * DSZ + 255) / 256, 256, 0, stream>>>(table, W1_w, W2_w, E1, E2);
    // 2. c[t]
    c_kernel<<<NT, 256, 0, stream>>>(E1, E2, CV);
    // 3. P1 = h @ W1_top + W1_b ; P2 = h @ W2_top + W2_b
    gemm_bias<false><<<dim3(DSZ / 64, nBS / 64, 1), 256, 0, stream>>>(
        h, W1_w, W1_b, P1, HID, HID, DSZ, DSZ, 0, 0, 0);
    gemm_bias<false><<<dim3(DSZ / 64, nBS / 64, 1), 256, 0, stream>>>(
        h, W2_w, W2_b, P2, HID, HID, DSZ, DSZ, 0, 0, 0);
    // 4. U/V
    uv_kernel<<<nBS, 256, 0, stream>>>(P1, P2, E1, E2, CV, U, V);
    // 5. Gram
    gram_kernel<<<dim3(SS / 32, SS / 32, BB), 256, 0, stream>>>(P1, P2, G);
    // 6. softmax -> Amat
    softmax_kernel<<<nBS, 128, 0, stream>>>(dep, G, U, V, Amat);
    // 7. AGG = Amat @ h   (batched: [128,128] @ [128,768])
    gemm_bias<false><<<dim3(HID / 64, SS / 64, BB), 256, 0, stream>>>(
        Amat, h, nullptr, AGG, SS, SS, HID, HID,
        (long)SS * SS, (long)SS * HID, (long)SS * HID);
    // 8. HSYN = relu(AGG @ gcn_w + gcn_b)
    gemm_bias<true><<<dim3(HID / 64, nBS / 64, 1), 256, 0, stream>>>(
        AGG, gcn_w, gcn_b, HSYN, HID, HID, HID, HID, 0, 0, 0);
    // 9. out = HSYN @ Wo_w + Wo_b
    gemm_bias<false><<<dim3(HID / 64, nBS / 64, 1), 256, 0, stream>>>(
        HSYN, Wo_w, Wo_b, out, DSZ, DSZ, HID, HID, 0, 0, 0);
}

// Round 2
// 186.562 us; speedup vs baseline: 1.9030x; 1.9030x over previous
//
#include <hip/hip_runtime.h>
#include <hip/hip_bf16.h>

#define BB 8
#define SS 128
#define HID 768
#define DEP 64
#define DSZ 768
#define NT 45
#define NEG -1000000000.0f

// ---------------------------------------------------------------------------
// E1[t,e] = sum_d table[t,d] * W1[(HID+d), e]   (and E2 with W2)
__global__ void e_kernel(const float* __restrict__ table,
                         const float* __restrict__ W1,
                         const float* __restrict__ W2,
                         float* __restrict__ E1, float* __restrict__ E2) {
    int idx = blockIdx.x * blockDim.x + threadIdx.x;
    if (idx >= NT * DSZ) return;
    int t = idx / DSZ, e = idx % DSZ;
    float s1 = 0.f, s2 = 0.f;
    for (int d = 0; d < DEP; ++d) {
        float td = table[t * DEP + d];
        s1 += td * W1[(HID + d) * DSZ + e];
        s2 += td * W2[(HID + d) * DSZ + e];
    }
    E1[idx] = s1;
    E2[idx] = s2;
}

// c[t] = dot(E1[t,:], E2[t,:])
__global__ void c_kernel(const float* __restrict__ E1, const float* __restrict__ E2,
                         float* __restrict__ cv) {
    int t = blockIdx.x;
    float s = 0.f;
    for (int e = threadIdx.x; e < DSZ; e += 256)
        s += E1[t * DSZ + e] * E2[t * DSZ + e];
    __shared__ float red[256];
    red[threadIdx.x] = s;
    __syncthreads();
    for (int w = 128; w >= 1; w >>= 1) {
        if (threadIdx.x < w) red[threadIdx.x] += red[threadIdx.x + w];
        __syncthreads();
    }
    if (threadIdx.x == 0) cv[t] = red[0];
}

// ---------------------------------------------------------------------------
// Shared GEMM tile body: 64x64 tile, Kc=16, 256 threads, 4x4 per thread.
// LDS pad 68 keeps rows 16B-aligned -> float4 ds_read_b128, conflict-free.
__device__ __forceinline__ void gemm_body(
    const float* __restrict__ Ab, const float* __restrict__ Bb,
    const float* __restrict__ bias, float* __restrict__ Cb,
    int kbeg, int kend, int lda, int ldb, int ldc,
    int row0, int col0, bool relu) {
    __shared__ float As[16][68];
    __shared__ float Bs[16][68];
    int tx = threadIdx.x & 15, ty = threadIdx.x >> 4;
    float acc[4][4] = {};
    for (int k0 = kbeg; k0 < kend; k0 += 16) {
#pragma unroll
        for (int l = 0; l < 4; ++l) {
            int idx = threadIdx.x + l * 256;  // 0..1023
            int r = idx >> 4, kk = idx & 15;
            As[kk][r] = Ab[(long)(row0 + r) * lda + k0 + kk];
            int kk2 = idx >> 6, cc = idx & 63;
            Bs[kk2][cc] = Bb[(long)(k0 + kk2) * ldb + col0 + cc];
        }
        __syncthreads();
#pragma unroll
        for (int kk = 0; kk < 16; ++kk) {
            float4 a4 = *(const float4*)&As[kk][ty * 4];
            float4 b4 = *(const float4*)&Bs[kk][tx * 4];
            float a[4] = {a4.x, a4.y, a4.z, a4.w};
            float b[4] = {b4.x, b4.y, b4.z, b4.w};
#pragma unroll
            for (int i = 0; i < 4; ++i)
#pragma unroll
                for (int j = 0; j < 4; ++j) acc[i][j] += a[i] * b[j];
        }
        __syncthreads();
    }
#pragma unroll
    for (int i = 0; i < 4; ++i) {
        int r = row0 + ty * 4 + i;
#pragma unroll
        for (int j = 0; j < 4; ++j) {
            int c = col0 + tx * 4 + j;
            float v = acc[i][j];
            if (bias) v += bias[c];
            if (relu) v = fmaxf(v, 0.f);
            Cb[(long)r * ldc + c] = v;
        }
    }
}

// Generic GEMM: batch and split-K folded into z. nsplit==1 -> direct+bias+relu.
__global__ __launch_bounds__(256) void gemm_k(
    const float* __restrict__ A, const float* __restrict__ B,
    const float* __restrict__ bias, float* __restrict__ C,
    int K, int nsplit, int lda, int ldb, int ldc,
    long sA, long sB, long sC, long splitStride, int relu) {
    int batch = blockIdx.z / nsplit, split = blockIdx.z % nsplit;
    int kc = K / nsplit;
    const float* Ab = A + (long)batch * sA;
    const float* Bb = B + (long)batch * sB;
    float* Cb = C + (long)batch * sC + (long)split * splitStride;
    gemm_body(Ab, Bb, nsplit == 1 ? bias : nullptr, Cb,
              split * kc, split * kc + kc, lda, ldb, ldc,
              blockIdx.y * 64, blockIdx.x * 64, relu && nsplit == 1);
}

// Dual GEMM for P1/P2 (same A, two Bs) with split-K; writes raw partials.
__global__ __launch_bounds__(256) void gemm_dual(
    const float* __restrict__ A, const float* __restrict__ B0,
    const float* __restrict__ B1, float* __restrict__ C0,
    float* __restrict__ C1, int K, int nsplit,
    int lda, int ldb, int ldc, long splitStride) {
    int which = blockIdx.z / nsplit, split = blockIdx.z % nsplit;
    int kc = K / nsplit;
    const float* Bb = which ? B1 : B0;
    float* Cb = (which ? C1 : C0) + (long)split * splitStride;
    gemm_body(A, Bb, nullptr, Cb, split * kc, split * kc + kc,
              lda, ldb, ldc, blockIdx.y * 64, blockIdx.x * 64, false);
}

// out = sum_s part[s] (+bias) (+relu), float4-vectorized.
__global__ __launch_bounds__(256) void reduce_k(
    const float* __restrict__ part, long splitStride, int nsplit,
    const float* __restrict__ bias, int ldc, float* __restrict__ out,
    long n, int relu) {
    long i = (long)blockIdx.x * blockDim.x + threadIdx.x;  // float4 idx
    if (i * 4 >= n) return;
    float4 s = ((const float4*)part)[i];
    for (int p = 1; p < nsplit; ++p) {
        float4 t = ((const float4*)(part + (long)p * splitStride))[i];
        s.x += t.x; s.y += t.y; s.z += t.z; s.w += t.w;
    }
    if (bias) {
        long col = (i * 4) % ldc;
        s.x += bias[col]; s.y += bias[col + 1];
        s.z += bias[col + 2]; s.w += bias[col + 3];
    }
    if (relu) {
        s.x = fmaxf(s.x, 0.f); s.y = fmaxf(s.y, 0.f);
        s.z = fmaxf(s.z, 0.f); s.w = fmaxf(s.w, 0.f);
    }
    ((float4*)out)[i] = s;
}

// ---------------------------------------------------------------------------
// Gram partials: Gp[split][b][i][j] = dot over K-chunk of P1,P2. Tile 32x32.
__global__ __launch_bounds__(256) void gram_kernel(
    const float* __restrict__ P1, const float* __restrict__ P2,
    float* __restrict__ Gp, int nsplit) {
    int b = blockIdx.z / nsplit, split = blockIdx.z % nsplit;
    int kc = DSZ / nsplit;
    int i0 = blockIdx.y * 32, j0 = blockIdx.x * 32;
    __shared__ float As[32][33];
    __shared__ float Bs[32][33];
    const float* p1 = P1 + (long)b * SS * DSZ;
    const float* p2 = P2 + (long)b * SS * DSZ;
    int tx = threadIdx.x % 32, ty = threadIdx.x / 32;
    float acc[4] = {0.f, 0.f, 0.f, 0.f};
    for (int k0 = split * kc; k0 < split * kc + kc; k0 += 32) {
#pragma unroll
        for (int l = 0; l < 4; ++l) {
            int idx = threadIdx.x + l * 256;
            int r = idx / 32, kk = idx % 32;
            As[kk][r] = p1[(long)(i0 + r) * DSZ + k0 + kk];
            Bs[kk][r] = p2[(long)(j0 + r) * DSZ + k0 + kk];
        }
        __syncthreads();
#pragma unroll
        for (int kk = 0; kk < 32; ++kk) {
            float bv = Bs[kk][tx];
#pragma unroll
            for (int i = 0; i < 4; ++i) acc[i] += As[kk][ty * 4 + i] * bv;
        }
        __syncthreads();
    }
#pragma unroll
    for (int i = 0; i < 4; ++i)
        Gp[(long)split * (BB * SS * SS) +
           ((long)b * SS + i0 + ty * 4 + i) * SS + j0 + tx] = acc[i];
}

// ---------------------------------------------------------------------------
// U[bs,t] = dot(P1[bs,:], E2[t,:]);  V[bs,t] = dot(P2[bs,:], E1[t,:]) + c[t]
__global__ __launch_bounds__(256) void uv_kernel(
    const float* __restrict__ P1, const float* __restrict__ P2,
    const float* __restrict__ E1, const float* __restrict__ E2,
    const float* __restrict__ cv, float* __restrict__ U, float* __restrict__ V) {
    int bs = blockIdx.x;
    __shared__ float p1[DSZ], p2[DSZ];
    for (int e = threadIdx.x; e < DSZ; e += 256) {
        p1[e] = P1[(long)bs * DSZ + e];
        p2[e] = P2[(long)bs * DSZ + e];
    }
    __syncthreads();
    int wave = threadIdx.x / 64, lane = threadIdx.x % 64;
    for (int t = wave; t < NT; t += 4) {
        float su = 0.f, sv = 0.f;
        for (int e = lane; e < DSZ; e += 64) {
            su += p1[e] * E2[t * DSZ + e];
            sv += p2[e] * E1[t * DSZ + e];
        }
        for (int off = 32; off >= 1; off >>= 1) {
            su += __shfl_down(su, off);
            sv += __shfl_down(sv, off);
        }
        if (lane == 0) {
            U[(long)bs * NT + t] = su;
            V[(long)bs * NT + t] = sv + cv[t];
        }
    }
}

// ---------------------------------------------------------------------------
// relevance (sum of Gram partials) + mask + softmax over j.
__global__ __launch_bounds__(128) void softmax_kernel(
    const int* __restrict__ dep, const float* __restrict__ Gp, int nsplit,
    const float* __restrict__ U, const float* __restrict__ V,
    float* __restrict__ A) {
    int bi = blockIdx.x;  // b*S + i
    int b = bi / SS;
    int j = threadIdx.x;
    int t = dep[(long)bi * SS + j];
    float r;
    if (t != 0) {
        float g = 0.f;
        for (int s = 0; s < nsplit; ++s)
            g += Gp[(long)s * (BB * SS * SS) + (long)bi * SS + j];
        r = g + U[(long)bi * NT + t] + V[((long)b * SS + j) * NT + t];
    } else {
        r = NEG;
    }
    float m = r;
    for (int off = 1; off < 64; off <<= 1) m = fmaxf(m, __shfl_xor(m, off));
    __shared__ float smax[2], ssum[2];
    if ((threadIdx.x & 63) == 0) smax[threadIdx.x >> 6] = m;
    __syncthreads();
    m = fmaxf(smax[0], smax[1]);
    float p = expf(r - m);
    float s = p;
    for (int off = 1; off < 64; off <<= 1) s += __shfl_xor(s, off);
    if ((threadIdx.x & 63) == 0) ssum[threadIdx.x >> 6] = s;
    __syncthreads();
    s = ssum[0] + ssum[1];
    A[(long)bi * SS + j] = p / s;
}

// ---------------------------------------------------------------------------
extern "C" void kernel_launch(void* const* d_in, const int* in_sizes, int n_in,
                              void* d_out, int out_size, void* d_ws, size_t ws_size,
                              hipStream_t stream) {
    const float* h      = (const float*)d_in[0];
    const int*   dep    = (const int*)d_in[1];
    const float* table  = (const float*)d_in[2];
    const float* W1_w   = (const float*)d_in[3];
    const float* W1_b   = (const float*)d_in[4];
    const float* W2_w   = (const float*)d_in[5];
    const float* W2_b   = (const float*)d_in[6];
    const float* gcn_w  = (const float*)d_in[7];
    const float* gcn_b  = (const float*)d_in[8];
    const float* Wo_w   = (const float*)d_in[9];
    const float* Wo_b   = (const float*)d_in[10];
    float* out = (float*)d_out;

    const long nBS = (long)BB * SS;       // 1024
    const long MN  = nBS * DSZ;           // 786432
    const long BSS = (long)BB * SS * SS;  // 131072

    float* ws = (float*)d_ws;
    long off = 0;
    float* P1   = ws + off; off += MN;
    float* P2   = ws + off; off += MN;
    float* E1   = ws + off; off += NT * DSZ;
    float* E2   = ws + off; off += NT * DSZ;
    float* CV   = ws + off; off += 64;
    float* U    = ws + off; off += nBS * NT;
    float* V    = ws + off; off += nBS * NT;
    float* Amat = ws + off; off += BSS;
    float* AGG  = ws + off; off += MN;
    float* HSYN = ws + off; off += MN;
    long baseSmall = off;                 // ~3.57M floats
    float* Gp   = ws + off; off += 4 * BSS;
    float* PART = ws + off; off += 4 * MN;
    long needBig = off;

    bool big = ws_size >= (size_t)needBig * sizeof(float);

    e_kernel<<<(NT * DSZ + 255) / 256, 256, 0, stream>>>(table, W1_w, W2_w, E1, E2);
    c_kernel<<<NT, 256, 0, stream>>>(E1, E2, CV);

    if (big) {
        // P1/P2: fused dual, split-K=2 -> 768 blocks
        gemm_dual<<<dim3(DSZ / 64, nBS / 64, 4), 256, 0, stream>>>(
            h, W1_w, W2_w, PART, PART + 2 * MN, HID, 2, HID, DSZ, DSZ, MN);
        reduce_k<<<(MN / 4 + 255) / 256, 256, 0, stream>>>(
            PART, MN, 2, W1_b, DSZ, P1, MN, 0);
        reduce_k<<<(MN / 4 + 255) / 256, 256, 0, stream>>>(
            PART + 2 * MN, MN, 2, W2_b, DSZ, P2, MN, 0);

        uv_kernel<<<nBS, 256, 0, stream>>>(P1, P2, E1, E2, CV, U, V);
        // Gram split-K=4 -> 512 blocks; partials summed inside softmax
        gram_kernel<<<dim3(SS / 32, SS / 32, BB * 4), 256, 0, stream>>>(P1, P2, Gp, 4);
        softmax_kernel<<<nBS, 128, 0, stream>>>(dep, Gp, 4, U, V, Amat);

        // AGG = Amat @ h, batched, split-K=2 -> 384 blocks
        gemm_k<<<dim3(HID / 64, SS / 64, BB * 2), 256, 0, stream>>>(
            Amat, h, nullptr, PART, SS, 2, SS, HID, HID,
            (long)SS * SS, (long)SS * HID, (long)SS * HID, MN, 0);
        reduce_k<<<(MN / 4 + 255) / 256, 256, 0, stream>>>(
            PART, MN, 2, nullptr, HID, AGG, MN, 0);

        // HSYN = relu(AGG @ gcn_w + b), split-K=4 -> 768 blocks
        gemm_k<<<dim3(HID / 64, nBS / 64, 4), 256, 0, stream>>>(
            AGG, gcn_w, nullptr, PART, HID, 4, HID, HID, HID, 0, 0, 0, MN, 0);
        reduce_k<<<(MN / 4 + 255) / 256, 256, 0, stream>>>(
            PART, MN, 4, gcn_b, HID, HSYN, MN, 1);

        // out = HSYN @ Wo_w + b, split-K=4
        gemm_k<<<dim3(HID / 64, nBS / 64, 4), 256, 0, stream>>>(
            HSYN, Wo_w, nullptr, PART, DSZ, 4, DSZ, HID, HID, 0, 0, 0, MN, 0);
        reduce_k<<<(MN / 4 + 255) / 256, 256, 0, stream>>>(
            PART, MN, 4, Wo_b, HID, out, MN, 0);
    } else {
        // Fallback: round-1 verified path (nsplit=1 direct), compact layout.
        float* G = ws + baseSmall;  // BSS floats
        gemm_k<<<dim3(DSZ / 64, nBS / 64, 1), 256, 0, stream>>>(
            h, W1_w, W1_b, P1, HID, 1, HID, DSZ, DSZ, 0, 0, 0, 0, 0);
        gemm_k<<<dim3(DSZ / 64, nBS / 64, 1), 256, 0, stream>>>(
            h, W2_w, W2_b, P2, HID, 1, HID, DSZ, DSZ, 0, 0, 0, 0, 0);
        uv_kernel<<<nBS, 256, 0, stream>>>(P1, P2, E1, E2, CV, U, V);
        gram_kernel<<<dim3(SS / 32, SS / 32, BB), 256, 0, stream>>>(P1, P2, G, 1);
        softmax_kernel<<<nBS, 128, 0, stream>>>(dep, G, 1, U, V, Amat);
        gemm_k<<<dim3(HID / 64, SS / 64, BB), 256, 0, stream>>>(
            Amat, h, nullptr, AGG, SS, 1, SS, HID, HID,
            (long)SS * SS, (long)SS * HID, (long)SS * HID, 0, 0);
        gemm_k<<<dim3(HID / 64, nBS / 64, 1), 256, 0, stream>>>(
            AGG, gcn_w, gcn_b, HSYN, HID, 1, HID, HID, HID, 0, 0, 0, 0, 1);
        gemm_k<<<dim3(HID / 64, nBS / 64, 1), 256, 0, stream>>>(
            HSYN, Wo_w, Wo_b, out, DSZ, 1, DSZ, HID, HID, 0, 0, 0, 0, 0);
    }
}

// Round 3
// 156.627 us; speedup vs baseline: 2.2667x; 1.1911x over previous
//
#include <hip/hip_runtime.h>
#include <hip/hip_bf16.h>

#define BB 8
#define SS 128
#define HID 768
#define DEP 64
#define DSZ 768
#define NT 45
#define NTP 48
#define NEG -1000000000.0f

// ---------------------------------------------------------------------------
// E1[t,e] = sum_d table[t,d] * W1[(HID+d), e]   (and E2 with W2)
__global__ void e_kernel(const float* __restrict__ table,
                         const float* __restrict__ W1,
                         const float* __restrict__ W2,
                         float* __restrict__ E1, float* __restrict__ E2) {
    int idx = blockIdx.x * blockDim.x + threadIdx.x;
    if (idx >= NT * DSZ) return;
    int t = idx / DSZ, e = idx % DSZ;
    float s1 = 0.f, s2 = 0.f;
    for (int d = 0; d < DEP; ++d) {
        float td = table[t * DEP + d];
        s1 += td * W1[(HID + d) * DSZ + e];
        s2 += td * W2[(HID + d) * DSZ + e];
    }
    E1[idx] = s1;
    E2[idx] = s2;
}

// c[t] = dot(E1[t,:], E2[t,:])
__global__ void c_kernel(const float* __restrict__ E1, const float* __restrict__ E2,
                         float* __restrict__ cv) {
    int t = blockIdx.x;
    float s = 0.f;
    for (int e = threadIdx.x; e < DSZ; e += 256)
        s += E1[t * DSZ + e] * E2[t * DSZ + e];
    __shared__ float red[256];
    red[threadIdx.x] = s;
    __syncthreads();
    for (int w = 128; w >= 1; w >>= 1) {
        if (threadIdx.x < w) red[threadIdx.x] += red[threadIdx.x + w];
        __syncthreads();
    }
    if (threadIdx.x == 0) cv[t] = red[0];
}

// ---------------------------------------------------------------------------
// Shared GEMM tile body: 64x64 tile, Kc=16, 256 threads, 4x4 per thread.
// LDS pad 68 keeps rows 16B-aligned -> float4 ds_read_b128, conflict-free.
__device__ __forceinline__ void gemm_body(
    const float* __restrict__ Ab, const float* __restrict__ Bb,
    const float* __restrict__ bias, float* __restrict__ Cb,
    int kbeg, int kend, int lda, int ldb, int ldc,
    int row0, int col0, bool relu) {
    __shared__ float As[16][68];
    __shared__ float Bs[16][68];
    int tx = threadIdx.x & 15, ty = threadIdx.x >> 4;
    float acc[4][4] = {};
    for (int k0 = kbeg; k0 < kend; k0 += 16) {
#pragma unroll
        for (int l = 0; l < 4; ++l) {
            int idx = threadIdx.x + l * 256;  // 0..1023
            int r = idx >> 4, kk = idx & 15;
            As[kk][r] = Ab[(long)(row0 + r) * lda + k0 + kk];
            int kk2 = idx >> 6, cc = idx & 63;
            Bs[kk2][cc] = Bb[(long)(k0 + kk2) * ldb + col0 + cc];
        }
        __syncthreads();
#pragma unroll
        for (int kk = 0; kk < 16; ++kk) {
            float4 a4 = *(const float4*)&As[kk][ty * 4];
            float4 b4 = *(const float4*)&Bs[kk][tx * 4];
            float a[4] = {a4.x, a4.y, a4.z, a4.w};
            float b[4] = {b4.x, b4.y, b4.z, b4.w};
#pragma unroll
            for (int i = 0; i < 4; ++i)
#pragma unroll
                for (int j = 0; j < 4; ++j) acc[i][j] += a[i] * b[j];
        }
        __syncthreads();
    }
#pragma unroll
    for (int i = 0; i < 4; ++i) {
        int r = row0 + ty * 4 + i;
#pragma unroll
        for (int j = 0; j < 4; ++j) {
            int c = col0 + tx * 4 + j;
            float v = acc[i][j];
            if (bias) v += bias[c];
            if (relu) v = fmaxf(v, 0.f);
            Cb[(long)r * ldc + c] = v;
        }
    }
}

// Generic GEMM: batch and split-K folded into z. nsplit==1 -> direct+bias+relu.
__global__ __launch_bounds__(256) void gemm_k(
    const float* __restrict__ A, const float* __restrict__ B,
    const float* __restrict__ bias, float* __restrict__ C,
    int K, int nsplit, int lda, int ldb, int ldc,
    long sA, long sB, long sC, long splitStride, int relu) {
    int batch = blockIdx.z / nsplit, split = blockIdx.z % nsplit;
    int kc = K / nsplit;
    const float* Ab = A + (long)batch * sA;
    const float* Bb = B + (long)batch * sB;
    float* Cb = C + (long)batch * sC + (long)split * splitStride;
    gemm_body(Ab, Bb, nsplit == 1 ? bias : nullptr, Cb,
              split * kc, split * kc + kc, lda, ldb, ldc,
              blockIdx.y * 64, blockIdx.x * 64, relu && nsplit == 1);
}

// Dual GEMM for P1/P2 (same A, two Bs) with split-K; writes raw partials.
__global__ __launch_bounds__(256) void gemm_dual(
    const float* __restrict__ A, const float* __restrict__ B0,
    const float* __restrict__ B1, float* __restrict__ C0,
    float* __restrict__ C1, int K, int nsplit,
    int lda, int ldb, int ldc, long splitStride) {
    int which = blockIdx.z / nsplit, split = blockIdx.z % nsplit;
    int kc = K / nsplit;
    const float* Bb = which ? B1 : B0;
    float* Cb = (which ? C1 : C0) + (long)split * splitStride;
    gemm_body(A, Bb, nullptr, Cb, split * kc, split * kc + kc,
              lda, ldb, ldc, blockIdx.y * 64, blockIdx.x * 64, false);
}

// out = sum_s part[s] (+bias) (+relu), float4-vectorized.
__global__ __launch_bounds__(256) void reduce_k(
    const float* __restrict__ part, long splitStride, int nsplit,
    const float* __restrict__ bias, int ldc, float* __restrict__ out,
    long n, int relu) {
    long i = (long)blockIdx.x * blockDim.x + threadIdx.x;  // float4 idx
    if (i * 4 >= n) return;
    float4 s = ((const float4*)part)[i];
    for (int p = 1; p < nsplit; ++p) {
        float4 t = ((const float4*)(part + (long)p * splitStride))[i];
        s.x += t.x; s.y += t.y; s.z += t.z; s.w += t.w;
    }
    if (bias) {
        long col = (i * 4) % ldc;
        s.x += bias[col]; s.y += bias[col + 1];
        s.z += bias[col + 2]; s.w += bias[col + 3];
    }
    if (relu) {
        s.x = fmaxf(s.x, 0.f); s.y = fmaxf(s.y, 0.f);
        s.z = fmaxf(s.z, 0.f); s.w = fmaxf(s.w, 0.f);
    }
    ((float4*)out)[i] = s;
}

// ---------------------------------------------------------------------------
// U/V as dual GEMM: Up[which][split][bs][t] partials.
//   which=0: U = P1 @ E2^T;  which=1: V = P2 @ E1^T
// Tile 64 rows x 48 cols (NT padded), 256 threads, 4x3 per thread, split-K.
// Grid: (nBS/64, nsplit, 2)
__global__ __launch_bounds__(256) void uv_gemm(
    const float* __restrict__ P1, const float* __restrict__ P2,
    const float* __restrict__ E1, const float* __restrict__ E2,
    float* __restrict__ Up, int nsplit) {
    int which = blockIdx.z, split = blockIdx.y;
    int row0 = blockIdx.x * 64;
    const float* P = which ? P2 : P1;
    const float* E = which ? E1 : E2;
    int kc = DSZ / nsplit;
    __shared__ float Ps[16][68];
    __shared__ float Es[16][48];
    int tx = threadIdx.x & 15, ty = threadIdx.x >> 4;
    float acc[4][3] = {};
    for (int k0 = split * kc; k0 < split * kc + kc; k0 += 16) {
#pragma unroll
        for (int l = 0; l < 4; ++l) {
            int idx = threadIdx.x + l * 256;
            int r = idx >> 4, kk = idx & 15;
            Ps[kk][r] = P[(long)(row0 + r) * DSZ + k0 + kk];
        }
#pragma unroll
        for (int l = 0; l < 3; ++l) {
            int idx = threadIdx.x + l * 256;  // 0..767 = 48 t x 16 kk
            int t = idx >> 4, kk = idx & 15;
            Es[kk][t] = (t < NT) ? E[(long)t * DSZ + k0 + kk] : 0.f;
        }
        __syncthreads();
#pragma unroll
        for (int kk = 0; kk < 16; ++kk) {
            float4 a4 = *(const float4*)&Ps[kk][ty * 4];
            float a[4] = {a4.x, a4.y, a4.z, a4.w};
            float b[3] = {Es[kk][tx * 3], Es[kk][tx * 3 + 1], Es[kk][tx * 3 + 2]};
#pragma unroll
            for (int i = 0; i < 4; ++i)
#pragma unroll
                for (int j = 0; j < 3; ++j) acc[i][j] += a[i] * b[j];
        }
        __syncthreads();
    }
    long base = ((long)which * nsplit + split) * ((long)BB * SS * NTP);
#pragma unroll
    for (int i = 0; i < 4; ++i)
#pragma unroll
        for (int j = 0; j < 3; ++j)
            Up[base + (long)(row0 + ty * 4 + i) * NTP + tx * 3 + j] = acc[i][j];
}

// U[idx] = sum_s Up[0][s][idx];  V[idx] = sum_s Up[1][s][idx] + c[t]
__global__ __launch_bounds__(256) void uv_reduce(
    const float* __restrict__ Up, const float* __restrict__ cv,
    float* __restrict__ U, float* __restrict__ V, int nsplit) {
    long n = (long)BB * SS * NTP;
    long idx = (long)blockIdx.x * blockDim.x + threadIdx.x;
    if (idx >= n) return;
    int t = idx % NTP;
    float su = 0.f, sv = 0.f;
    for (int s = 0; s < nsplit; ++s) {
        su += Up[(long)s * n + idx];
        sv += Up[((long)nsplit + s) * n + idx];
    }
    U[idx] = su;
    V[idx] = sv + (t < NT ? cv[t] : 0.f);
}

// ---------------------------------------------------------------------------
// Gram partials: Gp[split][b][i][j] = dot over K-chunk of P1,P2. Tile 32x32.
__global__ __launch_bounds__(256) void gram_kernel(
    const float* __restrict__ P1, const float* __restrict__ P2,
    float* __restrict__ Gp, int nsplit) {
    int b = blockIdx.z / nsplit, split = blockIdx.z % nsplit;
    int kc = DSZ / nsplit;
    int i0 = blockIdx.y * 32, j0 = blockIdx.x * 32;
    __shared__ float As[32][33];
    __shared__ float Bs[32][33];
    const float* p1 = P1 + (long)b * SS * DSZ;
    const float* p2 = P2 + (long)b * SS * DSZ;
    int tx = threadIdx.x % 32, ty = threadIdx.x / 32;
    float acc[4] = {0.f, 0.f, 0.f, 0.f};
    for (int k0 = split * kc; k0 < split * kc + kc; k0 += 32) {
#pragma unroll
        for (int l = 0; l < 4; ++l) {
            int idx = threadIdx.x + l * 256;
            int r = idx / 32, kk = idx % 32;
            As[kk][r] = p1[(long)(i0 + r) * DSZ + k0 + kk];
            Bs[kk][r] = p2[(long)(j0 + r) * DSZ + k0 + kk];
        }
        __syncthreads();
#pragma unroll
        for (int kk = 0; kk < 32; ++kk) {
            float bv = Bs[kk][tx];
#pragma unroll
            for (int i = 0; i < 4; ++i) acc[i] += As[kk][ty * 4 + i] * bv;
        }
        __syncthreads();
    }
#pragma unroll
    for (int i = 0; i < 4; ++i)
        Gp[(long)split * (BB * SS * SS) +
           ((long)b * SS + i0 + ty * 4 + i) * SS + j0 + tx] = acc[i];
}

// ---------------------------------------------------------------------------
// Legacy U/V kernel (fallback path only). Writes stride-NTP.
__global__ __launch_bounds__(256) void uv_kernel(
    const float* __restrict__ P1, const float* __restrict__ P2,
    const float* __restrict__ E1, const float* __restrict__ E2,
    const float* __restrict__ cv, float* __restrict__ U, float* __restrict__ V) {
    int bs = blockIdx.x;
    __shared__ float p1[DSZ], p2[DSZ];
    for (int e = threadIdx.x; e < DSZ; e += 256) {
        p1[e] = P1[(long)bs * DSZ + e];
        p2[e] = P2[(long)bs * DSZ + e];
    }
    __syncthreads();
    int wave = threadIdx.x / 64, lane = threadIdx.x % 64;
    for (int t = wave; t < NT; t += 4) {
        float su = 0.f, sv = 0.f;
        for (int e = lane; e < DSZ; e += 64) {
            su += p1[e] * E2[t * DSZ + e];
            sv += p2[e] * E1[t * DSZ + e];
        }
        for (int off = 32; off >= 1; off >>= 1) {
            su += __shfl_down(su, off);
            sv += __shfl_down(sv, off);
        }
        if (lane == 0) {
            U[(long)bs * NTP + t] = su;
            V[(long)bs * NTP + t] = sv + cv[t];
        }
    }
}

// ---------------------------------------------------------------------------
// relevance (sum of Gram partials) + mask + softmax over j.
__global__ __launch_bounds__(128) void softmax_kernel(
    const int* __restrict__ dep, const float* __restrict__ Gp, int nsplit,
    const float* __restrict__ U, const float* __restrict__ V,
    float* __restrict__ A) {
    int bi = blockIdx.x;  // b*S + i
    int b = bi / SS;
    int j = threadIdx.x;
    int t = dep[(long)bi * SS + j];
    float r;
    if (t != 0) {
        float g = 0.f;
        for (int s = 0; s < nsplit; ++s)
            g += Gp[(long)s * (BB * SS * SS) + (long)bi * SS + j];
        r = g + U[(long)bi * NTP + t] + V[((long)b * SS + j) * NTP + t];
    } else {
        r = NEG;
    }
    float m = r;
    for (int off = 1; off < 64; off <<= 1) m = fmaxf(m, __shfl_xor(m, off));
    __shared__ float smax[2], ssum[2];
    if ((threadIdx.x & 63) == 0) smax[threadIdx.x >> 6] = m;
    __syncthreads();
    m = fmaxf(smax[0], smax[1]);
    float p = expf(r - m);
    float s = p;
    for (int off = 1; off < 64; off <<= 1) s += __shfl_xor(s, off);
    if ((threadIdx.x & 63) == 0) ssum[threadIdx.x >> 6] = s;
    __syncthreads();
    s = ssum[0] + ssum[1];
    A[(long)bi * SS + j] = p / s;
}

// ---------------------------------------------------------------------------
extern "C" void kernel_launch(void* const* d_in, const int* in_sizes, int n_in,
                              void* d_out, int out_size, void* d_ws, size_t ws_size,
                              hipStream_t stream) {
    const float* h      = (const float*)d_in[0];
    const int*   dep    = (const int*)d_in[1];
    const float* table  = (const float*)d_in[2];
    const float* W1_w   = (const float*)d_in[3];
    const float* W1_b   = (const float*)d_in[4];
    const float* W2_w   = (const float*)d_in[5];
    const float* W2_b   = (const float*)d_in[6];
    const float* gcn_w  = (const float*)d_in[7];
    const float* gcn_b  = (const float*)d_in[8];
    const float* Wo_w   = (const float*)d_in[9];
    const float* Wo_b   = (const float*)d_in[10];
    float* out = (float*)d_out;

    const long nBS = (long)BB * SS;       // 1024
    const long MN  = nBS * DSZ;           // 786432
    const long BSS = (long)BB * SS * SS;  // 131072
    const long UVN = nBS * NTP;           // 49152

    float* ws = (float*)d_ws;
    long off = 0;
    float* P1   = ws + off; off += MN;
    float* P2   = ws + off; off += MN;
    float* E1   = ws + off; off += NT * DSZ;
    float* E2   = ws + off; off += NT * DSZ;
    float* CV   = ws + off; off += 64;
    float* U    = ws + off; off += UVN;
    float* V    = ws + off; off += UVN;
    float* Amat = ws + off; off += BSS;
    float* AGG  = ws + off; off += MN;
    float* HSYN = ws + off; off += MN;
    long baseSmall = off;
    float* Gp   = ws + off; off += 4 * BSS;
    float* PART = ws + off; off += 4 * MN;
    float* Up   = ws + off; off += 16 * UVN;  // 2 x 8 x 1024 x 48
    long needBig = off;

    bool big = ws_size >= (size_t)needBig * sizeof(float);

    e_kernel<<<(NT * DSZ + 255) / 256, 256, 0, stream>>>(table, W1_w, W2_w, E1, E2);
    c_kernel<<<NT, 256, 0, stream>>>(E1, E2, CV);

    if (big) {
        // P1/P2: fused dual, split-K=2 -> 768 blocks
        gemm_dual<<<dim3(DSZ / 64, nBS / 64, 4), 256, 0, stream>>>(
            h, W1_w, W2_w, PART, PART + 2 * MN, HID, 2, HID, DSZ, DSZ, MN);
        reduce_k<<<(MN / 4 + 255) / 256, 256, 0, stream>>>(
            PART, MN, 2, W1_b, DSZ, P1, MN, 0);
        reduce_k<<<(MN / 4 + 255) / 256, 256, 0, stream>>>(
            PART + 2 * MN, MN, 2, W2_b, DSZ, P2, MN, 0);

        // U/V as dual GEMM, split-K=8 -> 256 blocks
        uv_gemm<<<dim3(nBS / 64, 8, 2), 256, 0, stream>>>(P1, P2, E1, E2, Up, 8);
        uv_reduce<<<(UVN + 255) / 256, 256, 0, stream>>>(Up, CV, U, V, 8);

        // Gram split-K=4 -> 512 blocks; partials summed inside softmax
        gram_kernel<<<dim3(SS / 32, SS / 32, BB * 4), 256, 0, stream>>>(P1, P2, Gp, 4);
        softmax_kernel<<<nBS, 128, 0, stream>>>(dep, Gp, 4, U, V, Amat);

        // AGG = Amat @ h, batched, split-K=2 -> 384 blocks
        gemm_k<<<dim3(HID / 64, SS / 64, BB * 2), 256, 0, stream>>>(
            Amat, h, nullptr, PART, SS, 2, SS, HID, HID,
            (long)SS * SS, (long)SS * HID, (long)SS * HID, MN, 0);
        reduce_k<<<(MN / 4 + 255) / 256, 256, 0, stream>>>(
            PART, MN, 2, nullptr, HID, AGG, MN, 0);

        // HSYN = relu(AGG @ gcn_w + b), split-K=4 -> 768 blocks
        gemm_k<<<dim3(HID / 64, nBS / 64, 4), 256, 0, stream>>>(
            AGG, gcn_w, nullptr, PART, HID, 4, HID, HID, HID, 0, 0, 0, MN, 0);
        reduce_k<<<(MN / 4 + 255) / 256, 256, 0, stream>>>(
            PART, MN, 4, gcn_b, HID, HSYN, MN, 1);

        // out = HSYN @ Wo_w + b, split-K=4
        gemm_k<<<dim3(HID / 64, nBS / 64, 4), 256, 0, stream>>>(
            HSYN, Wo_w, nullptr, PART, DSZ, 4, DSZ, HID, HID, 0, 0, 0, MN, 0);
        reduce_k<<<(MN / 4 + 255) / 256, 256, 0, stream>>>(
            PART, MN, 4, Wo_b, HID, out, MN, 0);
    } else {
        // Fallback: verified nsplit=1 path, compact layout.
        float* G = ws + baseSmall;  // BSS floats
        gemm_k<<<dim3(DSZ / 64, nBS / 64, 1), 256, 0, stream>>>(
            h, W1_w, W1_b, P1, HID, 1, HID, DSZ, DSZ, 0, 0, 0, 0, 0);
        gemm_k<<<dim3(DSZ / 64, nBS / 64, 1), 256, 0, stream>>>(
            h, W2_w, W2_b, P2, HID, 1, HID, DSZ, DSZ, 0, 0, 0, 0, 0);
        uv_kernel<<<nBS, 256, 0, stream>>>(P1, P2, E1, E2, CV, U, V);
        gram_kernel<<<dim3(SS / 32, SS / 32, BB), 256, 0, stream>>>(P1, P2, G, 1);
        softmax_kernel<<<nBS, 128, 0, stream>>>(dep, G, 1, U, V, Amat);
        gemm_k<<<dim3(HID / 64, SS / 64, BB), 256, 0, stream>>>(
            Amat, h, nullptr, AGG, SS, 1, SS, HID, HID,
            (long)SS * SS, (long)SS * HID, (long)SS * HID, 0, 0);
        gemm_k<<<dim3(HID / 64, nBS / 64, 1), 256, 0, stream>>>(
            AGG, gcn_w, gcn_b, HSYN, HID, 1, HID, HID, HID, 0, 0, 0, 0, 1);
        gemm_k<<<dim3(HID / 64, nBS / 64, 1), 256, 0, stream>>>(
            HSYN, Wo_w, Wo_b, out, DSZ, 1, DSZ, HID, HID, 0, 0, 0, 0, 0);
    }
}

// Round 5
// 131.875 us; speedup vs baseline: 2.6921x; 1.1877x over previous
//
#include <hip/hip_runtime.h>
#include <hip/hip_bf16.h>

#define BB 8
#define SS 128
#define HID 768
#define DEP 64
#define DSZ 768
#define NT 45
#define NTP 48
#define NEG -1000000000.0f

typedef short bfv8 __attribute__((ext_vector_type(8)));
typedef float f32x4 __attribute__((ext_vector_type(4)));

__device__ __forceinline__ unsigned short f2bf(float x) {
    unsigned int u; __builtin_memcpy(&u, &x, 4);
    u += 0x7fffu + ((u >> 16) & 1u);
    return (unsigned short)(u >> 16);
}
__device__ __forceinline__ float bf2f(unsigned short h) {
    unsigned int u = ((unsigned int)h) << 16;
    float f; __builtin_memcpy(&f, &u, 4);
    return f;
}

// ---------------------------------------------------------------------------
// E: slot0 = E2 = table @ W2[HID:], slot1 = E1 = table @ W1[HID:].
// fp32 [2][48][768] for c_kernel; bf16 hi/lo for the UV MFMA GEMM.
__global__ void e_kernel(const float* __restrict__ table,
                         const float* __restrict__ W1,
                         const float* __restrict__ W2,
                         float* __restrict__ Ef,
                         unsigned short* __restrict__ Ehi,
                         unsigned short* __restrict__ Elo) {
    int idx = blockIdx.x * blockDim.x + threadIdx.x;
    if (idx >= NTP * DSZ) return;
    int t = idx / DSZ, e = idx % DSZ;
    float s1 = 0.f, s2 = 0.f;
    if (t < NT)
        for (int d = 0; d < DEP; ++d) {
            float td = table[t * DEP + d];
            s1 += td * W1[(HID + d) * DSZ + e];
            s2 += td * W2[(HID + d) * DSZ + e];
        }
    const long EN = (long)NTP * DSZ;
    Ef[idx] = s2; Ef[EN + idx] = s1;
    unsigned short h2 = f2bf(s2), h1 = f2bf(s1);
    Ehi[idx] = h2;      Elo[idx] = f2bf(s2 - bf2f(h2));
    Ehi[EN + idx] = h1; Elo[EN + idx] = f2bf(s1 - bf2f(h1));
}

// c[t] = dot(E1[t,:], E2[t,:])
__global__ void c_kernel(const float* __restrict__ Ef, float* __restrict__ cv) {
    int t = blockIdx.x;
    const long EN = (long)NTP * DSZ;
    float s = 0.f;
    for (int e = threadIdx.x; e < DSZ; e += 256)
        s += Ef[(long)t * DSZ + e] * Ef[EN + (long)t * DSZ + e];
    __shared__ float red[256];
    red[threadIdx.x] = s;
    __syncthreads();
    for (int w = 128; w >= 1; w >>= 1) {
        if (threadIdx.x < w) red[threadIdx.x] += red[threadIdx.x + w];
        __syncthreads();
    }
    if (threadIdx.x == 0) cv[t] = red[0];
}

// ---------------------------------------------------------------------------
// fp32 -> bf16 hi/lo, elementwise (for h as A-operand).
__global__ __launch_bounds__(256) void conv_hilo(
    const float* __restrict__ x, unsigned short* __restrict__ hi,
    unsigned short* __restrict__ lo, long n) {
    long i = (long)blockIdx.x * 256 + threadIdx.x;
    if (i * 4 >= n) return;
    float4 v = ((const float4*)x)[i];
    ushort4 h, l;
    h.x = f2bf(v.x); l.x = f2bf(v.x - bf2f(h.x));
    h.y = f2bf(v.y); l.y = f2bf(v.y - bf2f(h.y));
    h.z = f2bf(v.z); l.z = f2bf(v.z - bf2f(h.z));
    h.w = f2bf(v.w); l.w = f2bf(v.w - bf2f(h.w));
    ((ushort4*)hi)[i] = h;
    ((ushort4*)lo)[i] = l;
}

// fp32 X [R][C] (ld=ldx, batched) -> bf16 hi/lo transposed [C][R].
// Grid: (C/32, R/32, batch), 256 threads.
__global__ __launch_bounds__(256) void conv_T(
    const float* __restrict__ X, int ldx, long sX,
    unsigned short* __restrict__ Thi, unsigned short* __restrict__ Tlo,
    int R, long sO) {
    int b = blockIdx.z;
    int r0 = blockIdx.y * 32, c0 = blockIdx.x * 32;
    __shared__ float tile[32][33];
    const float* Xb = X + (long)b * sX;
    int tr = threadIdx.x >> 5, tc = threadIdx.x & 31;
#pragma unroll
    for (int k = 0; k < 4; ++k)
        tile[tr + k * 8][tc] = Xb[(long)(r0 + tr + k * 8) * ldx + c0 + tc];
    __syncthreads();
#pragma unroll
    for (int k = 0; k < 4; ++k) {
        int i = tr + k * 8, j = tc;
        float v = tile[j][i];  // = X[r0+j][c0+i]
        unsigned short h = f2bf(v);
        long o = (long)b * sO + (long)(c0 + i) * R + r0 + j;
        Thi[o] = h;
        Tlo[o] = f2bf(v - bf2f(h));
    }
}

// ---------------------------------------------------------------------------
// Split-precision bf16 MFMA GEMM: C = A @ Bt^T  (A [M][K] hi/lo, Bt [N][K] hi/lo)
// D = Ahi*Bhi + Ahi*Blo + Alo*Bhi  (lo*lo dropped; rel err ~2^-17)
// Tile 128x128, BK=32, 256 threads = 4 waves (2x2), 4x4 16x16x32 frags/wave.
// z = batch*nsplit + split.  C partial fp32 at batch*sC + split*splitStride.
__global__ __launch_bounds__(256) void mfma_gemm(
    const unsigned short* __restrict__ Ahi, const unsigned short* __restrict__ Alo,
    const unsigned short* __restrict__ Bhi, const unsigned short* __restrict__ Blo,
    float* __restrict__ C, int K, int nsplit, int ldc, int Nvalid,
    long sA, long sB, long sC, long splitStride) {
    int batch = blockIdx.z / nsplit, split = blockIdx.z - batch * nsplit;
    int kc = K / nsplit;
    int kb = split * kc;
    const unsigned short* ah = Ahi + (long)batch * sA;
    const unsigned short* al = Alo + (long)batch * sA;
    const unsigned short* bh = Bhi + (long)batch * sB;
    const unsigned short* bl = Blo + (long)batch * sB;
    float* Cb = C + (long)batch * sC + (long)split * splitStride;
    int m0 = blockIdx.y * 128, n0 = blockIdx.x * 128;

    __shared__ __align__(16) unsigned short sAh[4096], sAl[4096], sBh[4096], sBl[4096];
    int tid = threadIdx.x;
    int lane = tid & 63, wave = tid >> 6;
    int wr = wave >> 1, wc = wave & 1;
    int q = lane >> 4, r = lane & 15;

    f32x4 acc[4][4];
#pragma unroll
    for (int i = 0; i < 4; ++i)
#pragma unroll
        for (int j = 0; j < 4; ++j) acc[i][j] = (f32x4){0.f, 0.f, 0.f, 0.f};

    // staging: seg s covers LDS shorts [s*8, s*8+8); row = s>>2, kseg = s&3
    int s0 = tid, s1 = tid + 256;
    int arow0 = s0 >> 2, ak0 = (s0 & 3) << 3;
    int arow1 = s1 >> 2, ak1 = (s1 & 3) << 3;
    const unsigned short* aP0 = ah + (long)(m0 + arow0) * K + ak0;
    const unsigned short* aP1 = ah + (long)(m0 + arow1) * K + ak1;
    const unsigned short* alP0 = al + (long)(m0 + arow0) * K + ak0;
    const unsigned short* alP1 = al + (long)(m0 + arow1) * K + ak1;
    bool bok0 = (n0 + arow0) < Nvalid, bok1 = (n0 + arow1) < Nvalid;
    const unsigned short* bP0 = bh + (long)(n0 + arow0) * K + ak0;
    const unsigned short* bP1 = bh + (long)(n0 + arow1) * K + ak1;
    const unsigned short* blP0 = bl + (long)(n0 + arow0) * K + ak0;
    const unsigned short* blP1 = bl + (long)(n0 + arow1) * K + ak1;
    const bfv8 zz = (bfv8){0, 0, 0, 0, 0, 0, 0, 0};

    int aOff[4], bOff[4];
#pragma unroll
    for (int f = 0; f < 4; ++f) {
        aOff[f] = (wr * 64 + f * 16 + r) * 32 + q * 8;
        bOff[f] = (wc * 64 + f * 16 + r) * 32 + q * 8;
    }

    for (int k0 = kb; k0 < kb + kc; k0 += 32) {
        bfv8 va0 = *(const bfv8*)(aP0 + k0);
        bfv8 va1 = *(const bfv8*)(aP1 + k0);
        bfv8 wa0 = *(const bfv8*)(alP0 + k0);
        bfv8 wa1 = *(const bfv8*)(alP1 + k0);
        bfv8 vb0 = bok0 ? *(const bfv8*)(bP0 + k0) : zz;
        bfv8 vb1 = bok1 ? *(const bfv8*)(bP1 + k0) : zz;
        bfv8 wb0 = bok0 ? *(const bfv8*)(blP0 + k0) : zz;
        bfv8 wb1 = bok1 ? *(const bfv8*)(blP1 + k0) : zz;
        __syncthreads();
        *(bfv8*)(sAh + s0 * 8) = va0;
        *(bfv8*)(sAh + s1 * 8) = va1;
        *(bfv8*)(sAl + s0 * 8) = wa0;
        *(bfv8*)(sAl + s1 * 8) = wa1;
        *(bfv8*)(sBh + s0 * 8) = vb0;
        *(bfv8*)(sBh + s1 * 8) = vb1;
        *(bfv8*)(sBl + s0 * 8) = wb0;
        *(bfv8*)(sBl + s1 * 8) = wb1;
        __syncthreads();

        bfv8 bh_r[4], bl_r[4];
#pragma unroll
        for (int fc = 0; fc < 4; ++fc) {
            bh_r[fc] = *(const bfv8*)(sBh + bOff[fc]);
            bl_r[fc] = *(const bfv8*)(sBl + bOff[fc]);
        }
#pragma unroll
        for (int fr = 0; fr < 4; ++fr) {
            bfv8 a_h = *(const bfv8*)(sAh + aOff[fr]);
            bfv8 a_l = *(const bfv8*)(sAl + aOff[fr]);
#pragma unroll
            for (int fc = 0; fc < 4; ++fc) {
                acc[fr][fc] = __builtin_amdgcn_mfma_f32_16x16x32_bf16(a_h, bh_r[fc], acc[fr][fc], 0, 0, 0);
                acc[fr][fc] = __builtin_amdgcn_mfma_f32_16x16x32_bf16(a_h, bl_r[fc], acc[fr][fc], 0, 0, 0);
                acc[fr][fc] = __builtin_amdgcn_mfma_f32_16x16x32_bf16(a_l, bh_r[fc], acc[fr][fc], 0, 0, 0);
            }
        }
    }
#pragma unroll
    for (int fr = 0; fr < 4; ++fr) {
        int rr = m0 + wr * 64 + fr * 16 + q * 4;
#pragma unroll
        for (int fc = 0; fc < 4; ++fc) {
            int cc = n0 + wc * 64 + fc * 16 + r;
            if (cc < Nvalid) {
#pragma unroll
                for (int i = 0; i < 4; ++i)
                    Cb[(long)(rr + i) * ldc + cc] = acc[fr][fc][i];
            }
        }
    }
}

// ---------------------------------------------------------------------------
// sum split partials (+bias)(+relu) -> fp32 or bf16 hi/lo.
template <int HILO>
__global__ __launch_bounds__(256) void reduce_k2(
    const float* __restrict__ part, long splitStride, int nsplit,
    const float* __restrict__ bias, int ldc, float* __restrict__ outf,
    unsigned short* __restrict__ ohi, unsigned short* __restrict__ olo,
    long n, int relu) {
    long i = (long)blockIdx.x * 256 + threadIdx.x;
    if (i * 4 >= n) return;
    float4 s = ((const float4*)part)[i];
    for (int p = 1; p < nsplit; ++p) {
        float4 t = ((const float4*)(part + (long)p * splitStride))[i];
        s.x += t.x; s.y += t.y; s.z += t.z; s.w += t.w;
    }
    if (bias) {
        long col = (i * 4) % ldc;
        s.x += bias[col]; s.y += bias[col + 1];
        s.z += bias[col + 2]; s.w += bias[col + 3];
    }
    if (relu) {
        s.x = fmaxf(s.x, 0.f); s.y = fmaxf(s.y, 0.f);
        s.z = fmaxf(s.z, 0.f); s.w = fmaxf(s.w, 0.f);
    }
    if (HILO) {
        ushort4 h, l;
        h.x = f2bf(s.x); l.x = f2bf(s.x - bf2f(h.x));
        h.y = f2bf(s.y); l.y = f2bf(s.y - bf2f(h.y));
        h.z = f2bf(s.z); l.z = f2bf(s.z - bf2f(h.z));
        h.w = f2bf(s.w); l.w = f2bf(s.w - bf2f(h.w));
        ((ushort4*)ohi)[i] = h;
        ((ushort4*)olo)[i] = l;
    } else {
        ((float4*)outf)[i] = s;
    }
}

// U/V partial reduce: Up z-order = batch(U=0,V=1)*nsplit + split, each 1024*48.
__global__ __launch_bounds__(256) void uv_reduce(
    const float* __restrict__ Up, const float* __restrict__ cv,
    float* __restrict__ U, float* __restrict__ V, int nsplit) {
    const long n = (long)BB * SS * NTP;
    long idx = (long)blockIdx.x * 256 + threadIdx.x;
    if (idx >= n) return;
    int t = idx % NTP;
    float su = 0.f, sv = 0.f;
    for (int s = 0; s < nsplit; ++s) {
        su += Up[(long)s * n + idx];
        sv += Up[((long)nsplit + s) * n + idx];
    }
    U[idx] = su;
    V[idx] = sv + (t < NT ? cv[t] : 0.f);
}

// ---------------------------------------------------------------------------
// relevance (sum split partials of G) + mask + softmax over j.
// gbase = bi*SS + j + b*batchExtra; splits at +s*splitStride.
// HILO=1: emit A as bf16 hi/lo (for MFMA AGG); HILO=0: fp32.
template <int HILO>
__global__ __launch_bounds__(128) void softmax_kernel(
    const int* __restrict__ dep, const float* __restrict__ Gp, int nsplit,
    long splitStride, long batchExtra,
    const float* __restrict__ U, const float* __restrict__ V,
    float* __restrict__ Af, unsigned short* __restrict__ Ahi,
    unsigned short* __restrict__ Alo) {
    int bi = blockIdx.x;
    int b = bi >> 7;
    int j = threadIdx.x;
    int t = dep[(long)bi * SS + j];
    float r;
    if (t != 0) {
        long gbase = (long)bi * SS + j + (long)b * batchExtra;
        float g = 0.f;
        for (int s = 0; s < nsplit; ++s) g += Gp[gbase + (long)s * splitStride];
        r = g + U[(long)bi * NTP + t] + V[((long)b * SS + j) * NTP + t];
    } else {
        r = NEG;
    }
    float m = r;
    for (int off = 1; off < 64; off <<= 1) m = fmaxf(m, __shfl_xor(m, off));
    __shared__ float smax[2], ssum[2];
    if ((threadIdx.x & 63) == 0) smax[threadIdx.x >> 6] = m;
    __syncthreads();
    m = fmaxf(smax[0], smax[1]);
    float p = expf(r - m);
    float s = p;
    for (int off = 1; off < 64; off <<= 1) s += __shfl_xor(s, off);
    if ((threadIdx.x & 63) == 0) ssum[threadIdx.x >> 6] = s;
    __syncthreads();
    s = ssum[0] + ssum[1];
    float v = p / s;
    if (HILO) {
        unsigned short h = f2bf(v);
        Ahi[(long)bi * SS + j] = h;
        Alo[(long)bi * SS + j] = f2bf(v - bf2f(h));
    } else {
        Af[(long)bi * SS + j] = v;
    }
}

// ===========================================================================
// Legacy fp32 path (ws-size fallback) — verified in rounds 1-3.
__device__ __forceinline__ void gemm_body(
    const float* __restrict__ Ab, const float* __restrict__ Bb,
    const float* __restrict__ bias, float* __restrict__ Cb,
    int kbeg, int kend, int lda, int ldb, int ldc,
    int row0, int col0, bool relu) {
    __shared__ float As[16][68];
    __shared__ float Bs[16][68];
    int tx = threadIdx.x & 15, ty = threadIdx.x >> 4;
    float acc[4][4] = {};
    for (int k0 = kbeg; k0 < kend; k0 += 16) {
#pragma unroll
        for (int l = 0; l < 4; ++l) {
            int idx = threadIdx.x + l * 256;
            int r = idx >> 4, kk = idx & 15;
            As[kk][r] = Ab[(long)(row0 + r) * lda + k0 + kk];
            int kk2 = idx >> 6, cc = idx & 63;
            Bs[kk2][cc] = Bb[(long)(k0 + kk2) * ldb + col0 + cc];
        }
        __syncthreads();
#pragma unroll
        for (int kk = 0; kk < 16; ++kk) {
            float4 a4 = *(const float4*)&As[kk][ty * 4];
            float4 b4 = *(const float4*)&Bs[kk][tx * 4];
            float a[4] = {a4.x, a4.y, a4.z, a4.w};
            float b[4] = {b4.x, b4.y, b4.z, b4.w};
#pragma unroll
            for (int i = 0; i < 4; ++i)
#pragma unroll
                for (int j = 0; j < 4; ++j) acc[i][j] += a[i] * b[j];
        }
        __syncthreads();
    }
#pragma unroll
    for (int i = 0; i < 4; ++i) {
        int r = row0 + ty * 4 + i;
#pragma unroll
        for (int j = 0; j < 4; ++j) {
            int c = col0 + tx * 4 + j;
            float v = acc[i][j];
            if (bias) v += bias[c];
            if (relu) v = fmaxf(v, 0.f);
            Cb[(long)r * ldc + c] = v;
        }
    }
}

__global__ __launch_bounds__(256) void gemm_k(
    const float* __restrict__ A, const float* __restrict__ B,
    const float* __restrict__ bias, float* __restrict__ C,
    int K, int nsplit, int lda, int ldb, int ldc,
    long sA, long sB, long sC, long splitStride, int relu) {
    int batch = blockIdx.z / nsplit, split = blockIdx.z % nsplit;
    int kc = K / nsplit;
    const float* Ab = A + (long)batch * sA;
    const float* Bb = B + (long)batch * sB;
    float* Cb = C + (long)batch * sC + (long)split * splitStride;
    gemm_body(Ab, Bb, nsplit == 1 ? bias : nullptr, Cb,
              split * kc, split * kc + kc, lda, ldb, ldc,
              blockIdx.y * 64, blockIdx.x * 64, relu && nsplit == 1);
}

__global__ __launch_bounds__(256) void gram32(
    const float* __restrict__ P1, const float* __restrict__ P2,
    float* __restrict__ Gp) {
    int b = blockIdx.z;
    int i0 = blockIdx.y * 32, j0 = blockIdx.x * 32;
    __shared__ float As[32][33];
    __shared__ float Bs[32][33];
    const float* p1 = P1 + (long)b * SS * DSZ;
    const float* p2 = P2 + (long)b * SS * DSZ;
    int tx = threadIdx.x % 32, ty = threadIdx.x / 32;
    float acc[4] = {0.f, 0.f, 0.f, 0.f};
    for (int k0 = 0; k0 < DSZ; k0 += 32) {
#pragma unroll
        for (int l = 0; l < 4; ++l) {
            int idx = threadIdx.x + l * 256;
            int r = idx / 32, kk = idx % 32;
            As[kk][r] = p1[(long)(i0 + r) * DSZ + k0 + kk];
            Bs[kk][r] = p2[(long)(j0 + r) * DSZ + k0 + kk];
        }
        __syncthreads();
#pragma unroll
        for (int kk = 0; kk < 32; ++kk) {
            float bv = Bs[kk][tx];
#pragma unroll
            for (int i = 0; i < 4; ++i) acc[i] += As[kk][ty * 4 + i] * bv;
        }
        __syncthreads();
    }
#pragma unroll
    for (int i = 0; i < 4; ++i)
        Gp[((long)b * SS + i0 + ty * 4 + i) * SS + j0 + tx] = acc[i];
}

__global__ __launch_bounds__(256) void uv_kernel(
    const float* __restrict__ P1, const float* __restrict__ P2,
    const float* __restrict__ E1, const float* __restrict__ E2,
    const float* __restrict__ cv, float* __restrict__ U, float* __restrict__ V) {
    int bs = blockIdx.x;
    __shared__ float p1[DSZ], p2[DSZ];
    for (int e = threadIdx.x; e < DSZ; e += 256) {
        p1[e] = P1[(long)bs * DSZ + e];
        p2[e] = P2[(long)bs * DSZ + e];
    }
    __syncthreads();
    int wave = threadIdx.x / 64, lane = threadIdx.x % 64;
    for (int t = wave; t < NT; t += 4) {
        float su = 0.f, sv = 0.f;
        for (int e = lane; e < DSZ; e += 64) {
            su += p1[e] * E2[(long)t * DSZ + e];
            sv += p2[e] * E1[(long)t * DSZ + e];
        }
        for (int off = 32; off >= 1; off >>= 1) {
            su += __shfl_down(su, off);
            sv += __shfl_down(sv, off);
        }
        if (lane == 0) {
            U[(long)bs * NTP + t] = su;
            V[(long)bs * NTP + t] = sv + cv[t];
        }
    }
}

// ---------------------------------------------------------------------------
extern "C" void kernel_launch(void* const* d_in, const int* in_sizes, int n_in,
                              void* d_out, int out_size, void* d_ws, size_t ws_size,
                              hipStream_t stream) {
    const float* h      = (const float*)d_in[0];
    const int*   dep    = (const int*)d_in[1];
    const float* table  = (const float*)d_in[2];
    const float* W1_w   = (const float*)d_in[3];
    const float* W1_b   = (const float*)d_in[4];
    const float* W2_w   = (const float*)d_in[5];
    const float* W2_b   = (const float*)d_in[6];
    const float* gcn_w  = (const float*)d_in[7];
    const float* gcn_b  = (const float*)d_in[8];
    const float* Wo_w   = (const float*)d_in[9];
    const float* Wo_b   = (const float*)d_in[10];
    float* out = (float*)d_out;

    const long nBS = (long)BB * SS;        // 1024
    const long MN  = nBS * DSZ;            // 786432
    const long BSS = (long)BB * SS * SS;   // 131072
    const long UVN = nBS * NTP;            // 49152
    const long EN  = (long)NTP * DSZ;      // 36864
    const long WN  = (long)DSZ * HID;      // 589824
    const long BSD = (long)SS * DSZ;       // 98304

    char* base = (char*)d_ws;
    size_t off = 0;
    auto alloc = [&](size_t bytes) -> void* {
        void* p = base + off;
        off += (bytes + 255) & ~(size_t)255;
        return p;
    };

    float* Ef    = (float*)alloc(2 * EN * 4);
    float* CV    = (float*)alloc(256);
    float* U     = (float*)alloc(UVN * 4);
    float* V     = (float*)alloc(UVN * 4);
    float* PART  = (float*)alloc(4 * MN * 4);   // shared by all partial stages
    unsigned short* EtHi = (unsigned short*)alloc(2 * EN * 2);
    unsigned short* EtLo = (unsigned short*)alloc(2 * EN * 2);
    unsigned short* hHi  = (unsigned short*)alloc(MN * 2);
    unsigned short* hLo  = (unsigned short*)alloc(MN * 2);
    unsigned short* htHi = (unsigned short*)alloc(MN * 2);
    unsigned short* htLo = (unsigned short*)alloc(MN * 2);
    unsigned short* WtHi = (unsigned short*)alloc(2 * WN * 2);
    unsigned short* WtLo = (unsigned short*)alloc(2 * WN * 2);
    unsigned short* gTHi = (unsigned short*)alloc(WN * 2);
    unsigned short* gTLo = (unsigned short*)alloc(WN * 2);
    unsigned short* oTHi = (unsigned short*)alloc(WN * 2);
    unsigned short* oTLo = (unsigned short*)alloc(WN * 2);
    unsigned short* Phi  = (unsigned short*)alloc(2 * MN * 2);
    unsigned short* Plo  = (unsigned short*)alloc(2 * MN * 2);
    unsigned short* AmHi = (unsigned short*)alloc(BSS * 2);
    unsigned short* AmLo = (unsigned short*)alloc(BSS * 2);
    unsigned short* AGHi = (unsigned short*)alloc(MN * 2);
    unsigned short* AGLo = (unsigned short*)alloc(MN * 2);
    unsigned short* HSHi = (unsigned short*)alloc(MN * 2);
    unsigned short* HSLo = (unsigned short*)alloc(MN * 2);
    size_t needBig = off;

    if (ws_size >= needBig) {
        e_kernel<<<(NTP * DSZ + 255) / 256, 256, 0, stream>>>(table, W1_w, W2_w, Ef, EtHi, EtLo);
        c_kernel<<<NT, 256, 0, stream>>>(Ef, CV);

        // conversions
        conv_hilo<<<(MN / 4 + 255) / 256, 256, 0, stream>>>(h, hHi, hLo, MN);
        conv_T<<<dim3(HID / 32, SS / 32, BB), 256, 0, stream>>>(h, HID, BSD, htHi, htLo, SS, BSD);
        conv_T<<<dim3(DSZ / 32, HID / 32, 1), 256, 0, stream>>>(W1_w, DSZ, 0, WtHi, WtLo, HID, 0);
        conv_T<<<dim3(DSZ / 32, HID / 32, 1), 256, 0, stream>>>(W2_w, DSZ, 0, WtHi + WN, WtLo + WN, HID, 0);
        conv_T<<<dim3(HID / 32, HID / 32, 1), 256, 0, stream>>>(gcn_w, HID, 0, gTHi, gTLo, HID, 0);
        conv_T<<<dim3(HID / 32, DSZ / 32, 1), 256, 0, stream>>>(Wo_w, HID, 0, oTHi, oTLo, DSZ, 0);

        // P1/P2 = h @ {W1,W2}[:HID] + b   (dual via batch, split-K=2 -> 384 blk)
        mfma_gemm<<<dim3(6, 8, 4), 256, 0, stream>>>(
            hHi, hLo, WtHi, WtLo, PART, HID, 2, DSZ, DSZ, 0, WN, 2 * MN, MN);
        reduce_k2<1><<<(MN / 4 + 255) / 256, 256, 0, stream>>>(
            PART, MN, 2, W1_b, DSZ, nullptr, Phi, Plo, MN, 0);
        reduce_k2<1><<<(MN / 4 + 255) / 256, 256, 0, stream>>>(
            PART + 2 * MN, MN, 2, W2_b, DSZ, nullptr, Phi + MN, Plo + MN, MN, 0);

        // U = P1@E2^T, V = P2@E1^T (+c)   split-K=4 -> 64 blk
        mfma_gemm<<<dim3(1, 8, 8), 256, 0, stream>>>(
            Phi, Plo, EtHi, EtLo, PART, DSZ, 4, NTP, NTP, MN, EN, 4 * UVN, UVN);
        uv_reduce<<<(UVN + 255) / 256, 256, 0, stream>>>(PART, CV, U, V, 4);

        // G[b] = P1_b @ P2_b^T   split-K=4 -> 32 blk, partials [b][s][128*128]
        mfma_gemm<<<dim3(1, 1, 32), 256, 0, stream>>>(
            Phi, Plo, Phi + MN, Plo + MN, PART, DSZ, 4, SS, SS, BSD, BSD,
            4 * (long)SS * SS, (long)SS * SS);
        softmax_kernel<1><<<nBS, 128, 0, stream>>>(
            dep, PART, 4, (long)SS * SS, 3L * SS * SS, U, V, nullptr, AmHi, AmLo);

        // AGG = A @ h (batched, K=128) -> 48 blk; then hi/lo convert
        mfma_gemm<<<dim3(6, 1, 8), 256, 0, stream>>>(
            AmHi, AmLo, htHi, htLo, PART, SS, 1, HID, HID, (long)SS * SS, BSD, BSD, 0);
        reduce_k2<1><<<(MN / 4 + 255) / 256, 256, 0, stream>>>(
            PART, 0, 1, nullptr, HID, nullptr, AGHi, AGLo, MN, 0);

        // HSYN = relu(AGG @ gcn + b)   split-K=4 -> 192 blk
        mfma_gemm<<<dim3(6, 8, 4), 256, 0, stream>>>(
            AGHi, AGLo, gTHi, gTLo, PART, HID, 4, HID, HID, 0, 0, 0, MN);
        reduce_k2<1><<<(MN / 4 + 255) / 256, 256, 0, stream>>>(
            PART, MN, 4, gcn_b, HID, nullptr, HSHi, HSLo, MN, 1);

        // out = HSYN @ Wo + b
        mfma_gemm<<<dim3(6, 8, 4), 256, 0, stream>>>(
            HSHi, HSLo, oTHi, oTLo, PART, DSZ, 4, HID, HID, 0, 0, 0, MN);
        reduce_k2<0><<<(MN / 4 + 255) / 256, 256, 0, stream>>>(
            PART, MN, 4, Wo_b, HID, out, nullptr, nullptr, MN, 0);
    } else {
        // Fallback: verified fp32 nsplit=1 path, compact layout.
        float* ws = (float*)d_ws;
        long o2 = 0;
        float* Ef2  = ws + o2; o2 += 2 * EN;
        float* CV2  = ws + o2; o2 += 64;
        float* P1   = ws + o2; o2 += MN;
        float* P2   = ws + o2; o2 += MN;
        float* Uf   = ws + o2; o2 += UVN;
        float* Vf   = ws + o2; o2 += UVN;
        float* G    = ws + o2; o2 += BSS;
        float* Amat = ws + o2; o2 += BSS;
        float* AGG  = ws + o2; o2 += MN;
        float* HSYN = ws + o2; o2 += MN;
        unsigned short* Eh2 = (unsigned short*)(ws + o2); o2 += EN;   // 2*EN shorts
        unsigned short* El2 = (unsigned short*)(ws + o2); o2 += EN;

        e_kernel<<<(NTP * DSZ + 255) / 256, 256, 0, stream>>>(table, W1_w, W2_w, Ef2, Eh2, El2);
        c_kernel<<<NT, 256, 0, stream>>>(Ef2, CV2);
        gemm_k<<<dim3(DSZ / 64, nBS / 64, 1), 256, 0, stream>>>(
            h, W1_w, W1_b, P1, HID, 1, HID, DSZ, DSZ, 0, 0, 0, 0, 0);
        gemm_k<<<dim3(DSZ / 64, nBS / 64, 1), 256, 0, stream>>>(
            h, W2_w, W2_b, P2, HID, 1, HID, DSZ, DSZ, 0, 0, 0, 0, 0);
        uv_kernel<<<nBS, 256, 0, stream>>>(P1, P2, Ef2 + EN, Ef2, CV2, Uf, Vf);
        gram32<<<dim3(SS / 32, SS / 32, BB), 256, 0, stream>>>(P1, P2, G);
        softmax_kernel<0><<<nBS, 128, 0, stream>>>(dep, G, 1, BSS, 0, Uf, Vf, Amat, nullptr, nullptr);
        gemm_k<<<dim3(HID / 64, SS / 64, BB), 256, 0, stream>>>(
            Amat, h, nullptr, AGG, SS, 1, SS, HID, HID,
            (long)SS * SS, BSD, BSD, 0, 0);
        gemm_k<<<dim3(HID / 64, nBS / 64, 1), 256, 0, stream>>>(
            AGG, gcn_w, gcn_b, HSYN, HID, 1, HID, HID, HID, 0, 0, 0, 0, 1);
        gemm_k<<<dim3(HID / 64, nBS / 64, 1), 256, 0, stream>>>(
            HSYN, Wo_w, Wo_b, out, DSZ, 1, DSZ, HID, HID, 0, 0, 0, 0, 0);
    }
}

// Round 6
// 115.904 us; speedup vs baseline: 3.0631x; 1.1378x over previous
//
#include <hip/hip_runtime.h>
#include <hip/hip_bf16.h>

#define BB 8
#define SS 128
#define HID 768
#define DEP 64
#define DSZ 768
#define NT 45
#define NTP 48
#define NEG -1000000000.0f

typedef short bfv8 __attribute__((ext_vector_type(8)));
typedef float f32x4 __attribute__((ext_vector_type(4)));

__device__ __forceinline__ unsigned short f2bf(float x) {
    unsigned int u; __builtin_memcpy(&u, &x, 4);
    u += 0x7fffu + ((u >> 16) & 1u);
    return (unsigned short)(u >> 16);
}
__device__ __forceinline__ float bf2f(unsigned short h) {
    unsigned int u = ((unsigned int)h) << 16;
    float f; __builtin_memcpy(&f, &u, 4);
    return f;
}

// ---------------------------------------------------------------------------
// E: slot0 = E2 = table @ W2[HID:], slot1 = E1 = table @ W1[HID:].
__global__ void e_kernel(const float* __restrict__ table,
                         const float* __restrict__ W1,
                         const float* __restrict__ W2,
                         float* __restrict__ Ef,
                         unsigned short* __restrict__ Ehi,
                         unsigned short* __restrict__ Elo) {
    int idx = blockIdx.x * blockDim.x + threadIdx.x;
    if (idx >= NTP * DSZ) return;
    int t = idx / DSZ, e = idx % DSZ;
    float s1 = 0.f, s2 = 0.f;
    if (t < NT)
        for (int d = 0; d < DEP; ++d) {
            float td = table[t * DEP + d];
            s1 += td * W1[(HID + d) * DSZ + e];
            s2 += td * W2[(HID + d) * DSZ + e];
        }
    const long EN = (long)NTP * DSZ;
    Ef[idx] = s2; Ef[EN + idx] = s1;
    unsigned short h2 = f2bf(s2), h1 = f2bf(s1);
    Ehi[idx] = h2;      Elo[idx] = f2bf(s2 - bf2f(h2));
    Ehi[EN + idx] = h1; Elo[EN + idx] = f2bf(s1 - bf2f(h1));
}

// c[t] = dot(E1[t,:], E2[t,:])
__global__ void c_kernel(const float* __restrict__ Ef, float* __restrict__ cv) {
    int t = blockIdx.x;
    const long EN = (long)NTP * DSZ;
    float s = 0.f;
    for (int e = threadIdx.x; e < DSZ; e += 256)
        s += Ef[(long)t * DSZ + e] * Ef[EN + (long)t * DSZ + e];
    __shared__ float red[256];
    red[threadIdx.x] = s;
    __syncthreads();
    for (int w = 128; w >= 1; w >>= 1) {
        if (threadIdx.x < w) red[threadIdx.x] += red[threadIdx.x + w];
        __syncthreads();
    }
    if (threadIdx.x == 0) cv[t] = red[0];
}

// ---------------------------------------------------------------------------
// fp32 -> bf16 hi/lo, elementwise (for h as A-operand of P-GEMM).
__global__ __launch_bounds__(256) void conv_hilo(
    const float* __restrict__ x, unsigned short* __restrict__ hi,
    unsigned short* __restrict__ lo, long n) {
    long i = (long)blockIdx.x * 256 + threadIdx.x;
    if (i * 4 >= n) return;
    float4 v = ((const float4*)x)[i];
    ushort4 h, l;
    h.x = f2bf(v.x); l.x = f2bf(v.x - bf2f(h.x));
    h.y = f2bf(v.y); l.y = f2bf(v.y - bf2f(h.y));
    h.z = f2bf(v.z); l.z = f2bf(v.z - bf2f(h.z));
    h.w = f2bf(v.w); l.w = f2bf(v.w - bf2f(h.w));
    ((ushort4*)hi)[i] = h;
    ((ushort4*)lo)[i] = l;
}

// fp32 X [R][C] (ld=ldx, batched) -> bf16 transposed [C][R]; LO: also write lo.
template <int LO>
__global__ __launch_bounds__(256) void conv_T(
    const float* __restrict__ X, int ldx, long sX,
    unsigned short* __restrict__ Thi, unsigned short* __restrict__ Tlo,
    int R, long sO) {
    int b = blockIdx.z;
    int r0 = blockIdx.y * 32, c0 = blockIdx.x * 32;
    __shared__ float tile[32][33];
    const float* Xb = X + (long)b * sX;
    int tr = threadIdx.x >> 5, tc = threadIdx.x & 31;
#pragma unroll
    for (int k = 0; k < 4; ++k)
        tile[tr + k * 8][tc] = Xb[(long)(r0 + tr + k * 8) * ldx + c0 + tc];
    __syncthreads();
#pragma unroll
    for (int k = 0; k < 4; ++k) {
        int i = tr + k * 8, j = tc;
        float v = tile[j][i];  // = X[r0+j][c0+i]
        unsigned short h = f2bf(v);
        long o = (long)b * sO + (long)(c0 + i) * R + r0 + j;
        Thi[o] = h;
        if (LO) Tlo[o] = f2bf(v - bf2f(h));
    }
}

// ---------------------------------------------------------------------------
// bf16 MFMA GEMM: C = A @ Bt^T  (A [M][K], Bt [N][K]).
// PREC==3: split-precision hi/lo, D = Ahi*Bhi + Ahi*Blo + Alo*Bhi (~2^-17).
// PREC==1: plain bf16 (hi only).
// OUT==0: fp32 C (partials; bias/relu ignored).  OUT==1: bf16 Cb direct,
//         bias+relu applied (requires nsplit==1).
// Tile 128x128, BK=32, 256 threads = 4 waves (2x2), 4x4 16x16x32 frags/wave.
template <int PREC, int OUT>
__global__ __launch_bounds__(256) void mfma_gemm(
    const unsigned short* __restrict__ Ahi, const unsigned short* __restrict__ Alo,
    const unsigned short* __restrict__ Bhi, const unsigned short* __restrict__ Blo,
    float* __restrict__ C, unsigned short* __restrict__ Cb16,
    const float* __restrict__ bias, int relu,
    int K, int nsplit, int ldc, int Nvalid,
    long sA, long sB, long sC, long splitStride) {
    int batch = blockIdx.z / nsplit, split = blockIdx.z - batch * nsplit;
    int kc = K / nsplit;
    int kb = split * kc;
    const unsigned short* ah = Ahi + (long)batch * sA;
    const unsigned short* bh = Bhi + (long)batch * sB;
    int m0 = blockIdx.y * 128, n0 = blockIdx.x * 128;

    __shared__ __align__(16) unsigned short sAh[4096], sBh[4096];
    __shared__ __align__(16) unsigned short sAl[PREC == 3 ? 4096 : 16];
    __shared__ __align__(16) unsigned short sBl[PREC == 3 ? 4096 : 16];
    int tid = threadIdx.x;
    int lane = tid & 63, wave = tid >> 6;
    int wr = wave >> 1, wc = wave & 1;
    int q = lane >> 4, r = lane & 15;

    f32x4 acc[4][4];
#pragma unroll
    for (int i = 0; i < 4; ++i)
#pragma unroll
        for (int j = 0; j < 4; ++j) acc[i][j] = (f32x4){0.f, 0.f, 0.f, 0.f};

    // staging: seg s covers LDS shorts [s*8, s*8+8); row = s>>2, kseg = s&3
    int s0 = tid, s1 = tid + 256;
    int arow0 = s0 >> 2, ak0 = (s0 & 3) << 3;
    int arow1 = s1 >> 2, ak1 = (s1 & 3) << 3;
    const unsigned short* aP0 = ah + (long)(m0 + arow0) * K + ak0;
    const unsigned short* aP1 = ah + (long)(m0 + arow1) * K + ak1;
    bool bok0 = (n0 + arow0) < Nvalid, bok1 = (n0 + arow1) < Nvalid;
    const unsigned short* bP0 = bh + (long)(n0 + arow0) * K + ak0;
    const unsigned short* bP1 = bh + (long)(n0 + arow1) * K + ak1;
    const unsigned short* alP0 = nullptr; const unsigned short* alP1 = nullptr;
    const unsigned short* blP0 = nullptr; const unsigned short* blP1 = nullptr;
    if constexpr (PREC == 3) {
        const unsigned short* al = Alo + (long)batch * sA;
        const unsigned short* bl = Blo + (long)batch * sB;
        alP0 = al + (long)(m0 + arow0) * K + ak0;
        alP1 = al + (long)(m0 + arow1) * K + ak1;
        blP0 = bl + (long)(n0 + arow0) * K + ak0;
        blP1 = bl + (long)(n0 + arow1) * K + ak1;
    }
    const bfv8 zz = (bfv8){0, 0, 0, 0, 0, 0, 0, 0};

    int aOff[4], bOff[4];
#pragma unroll
    for (int f = 0; f < 4; ++f) {
        aOff[f] = (wr * 64 + f * 16 + r) * 32 + q * 8;
        bOff[f] = (wc * 64 + f * 16 + r) * 32 + q * 8;
    }

    for (int k0 = kb; k0 < kb + kc; k0 += 32) {
        bfv8 va0 = *(const bfv8*)(aP0 + k0);
        bfv8 va1 = *(const bfv8*)(aP1 + k0);
        bfv8 vb0 = bok0 ? *(const bfv8*)(bP0 + k0) : zz;
        bfv8 vb1 = bok1 ? *(const bfv8*)(bP1 + k0) : zz;
        bfv8 wa0, wa1, wb0, wb1;
        if constexpr (PREC == 3) {
            wa0 = *(const bfv8*)(alP0 + k0);
            wa1 = *(const bfv8*)(alP1 + k0);
            wb0 = bok0 ? *(const bfv8*)(blP0 + k0) : zz;
            wb1 = bok1 ? *(const bfv8*)(blP1 + k0) : zz;
        }
        __syncthreads();
        *(bfv8*)(sAh + s0 * 8) = va0;
        *(bfv8*)(sAh + s1 * 8) = va1;
        *(bfv8*)(sBh + s0 * 8) = vb0;
        *(bfv8*)(sBh + s1 * 8) = vb1;
        if constexpr (PREC == 3) {
            *(bfv8*)(sAl + s0 * 8) = wa0;
            *(bfv8*)(sAl + s1 * 8) = wa1;
            *(bfv8*)(sBl + s0 * 8) = wb0;
            *(bfv8*)(sBl + s1 * 8) = wb1;
        }
        __syncthreads();

        bfv8 bh_r[4], bl_r[4];
#pragma unroll
        for (int fc = 0; fc < 4; ++fc) {
            bh_r[fc] = *(const bfv8*)(sBh + bOff[fc]);
            if constexpr (PREC == 3) bl_r[fc] = *(const bfv8*)(sBl + bOff[fc]);
        }
#pragma unroll
        for (int fr = 0; fr < 4; ++fr) {
            bfv8 a_h = *(const bfv8*)(sAh + aOff[fr]);
            bfv8 a_l;
            if constexpr (PREC == 3) a_l = *(const bfv8*)(sAl + aOff[fr]);
#pragma unroll
            for (int fc = 0; fc < 4; ++fc) {
                acc[fr][fc] = __builtin_amdgcn_mfma_f32_16x16x32_bf16(a_h, bh_r[fc], acc[fr][fc], 0, 0, 0);
                if constexpr (PREC == 3) {
                    acc[fr][fc] = __builtin_amdgcn_mfma_f32_16x16x32_bf16(a_h, bl_r[fc], acc[fr][fc], 0, 0, 0);
                    acc[fr][fc] = __builtin_amdgcn_mfma_f32_16x16x32_bf16(a_l, bh_r[fc], acc[fr][fc], 0, 0, 0);
                }
            }
        }
    }
    if constexpr (OUT == 0) {
        float* Cb = C + (long)batch * sC + (long)split * splitStride;
#pragma unroll
        for (int fr = 0; fr < 4; ++fr) {
            int rr = m0 + wr * 64 + fr * 16 + q * 4;
#pragma unroll
            for (int fc = 0; fc < 4; ++fc) {
                int cc = n0 + wc * 64 + fc * 16 + r;
                if (cc < Nvalid) {
#pragma unroll
                    for (int i = 0; i < 4; ++i)
                        Cb[(long)(rr + i) * ldc + cc] = acc[fr][fc][i];
                }
            }
        }
    } else {
        unsigned short* Cb = Cb16 + (long)batch * sC;
#pragma unroll
        for (int fr = 0; fr < 4; ++fr) {
            int rr = m0 + wr * 64 + fr * 16 + q * 4;
#pragma unroll
            for (int fc = 0; fc < 4; ++fc) {
                int cc = n0 + wc * 64 + fc * 16 + r;
                if (cc < Nvalid) {
                    float bv = bias ? bias[cc] : 0.f;
#pragma unroll
                    for (int i = 0; i < 4; ++i) {
                        float v = acc[fr][fc][i] + bv;
                        if (relu) v = fmaxf(v, 0.f);
                        Cb[(long)(rr + i) * ldc + cc] = f2bf(v);
                    }
                }
            }
        }
    }
}

// ---------------------------------------------------------------------------
// sum split partials (+bias)(+relu).  HILO: 0=fp32 out, 1=hi+lo, 2=hi only.
template <int HILO>
__global__ __launch_bounds__(256) void reduce_k2(
    const float* __restrict__ part, long splitStride, int nsplit,
    const float* __restrict__ bias, int ldc, float* __restrict__ outf,
    unsigned short* __restrict__ ohi, unsigned short* __restrict__ olo,
    long n, int relu) {
    long i = (long)blockIdx.x * 256 + threadIdx.x;
    if (i * 4 >= n) return;
    float4 s = ((const float4*)part)[i];
    for (int p = 1; p < nsplit; ++p) {
        float4 t = ((const float4*)(part + (long)p * splitStride))[i];
        s.x += t.x; s.y += t.y; s.z += t.z; s.w += t.w;
    }
    if (bias) {
        long col = (i * 4) % ldc;
        s.x += bias[col]; s.y += bias[col + 1];
        s.z += bias[col + 2]; s.w += bias[col + 3];
    }
    if (relu) {
        s.x = fmaxf(s.x, 0.f); s.y = fmaxf(s.y, 0.f);
        s.z = fmaxf(s.z, 0.f); s.w = fmaxf(s.w, 0.f);
    }
    if (HILO == 0) {
        ((float4*)outf)[i] = s;
    } else {
        ushort4 h;
        h.x = f2bf(s.x); h.y = f2bf(s.y); h.z = f2bf(s.z); h.w = f2bf(s.w);
        ((ushort4*)ohi)[i] = h;
        if (HILO == 1) {
            ushort4 l;
            l.x = f2bf(s.x - bf2f(h.x)); l.y = f2bf(s.y - bf2f(h.y));
            l.z = f2bf(s.z - bf2f(h.z)); l.w = f2bf(s.w - bf2f(h.w));
            ((ushort4*)olo)[i] = l;
        }
    }
}

// U/V partial reduce: Up z-order = which(U=0,V=1)*nsplit + split, each 1024*48.
__global__ __launch_bounds__(256) void uv_reduce(
    const float* __restrict__ Up, const float* __restrict__ cv,
    float* __restrict__ U, float* __restrict__ V, int nsplit) {
    const long n = (long)BB * SS * NTP;
    long idx = (long)blockIdx.x * 256 + threadIdx.x;
    if (idx >= n) return;
    int t = idx % NTP;
    float su = 0.f, sv = 0.f;
    for (int s = 0; s < nsplit; ++s) {
        su += Up[(long)s * n + idx];
        sv += Up[((long)nsplit + s) * n + idx];
    }
    U[idx] = su;
    V[idx] = sv + (t < NT ? cv[t] : 0.f);
}

// ---------------------------------------------------------------------------
// relevance (sum split partials of G) + mask + softmax over j.
// HILO==1: emit bf16 hi only (AGG GEMM is single-precision); 0: fp32.
template <int HILO>
__global__ __launch_bounds__(128) void softmax_kernel(
    const int* __restrict__ dep, const float* __restrict__ Gp, int nsplit,
    long splitStride, long batchExtra,
    const float* __restrict__ U, const float* __restrict__ V,
    float* __restrict__ Af, unsigned short* __restrict__ Ahi,
    unsigned short* __restrict__ Alo) {
    int bi = blockIdx.x;
    int b = bi >> 7;
    int j = threadIdx.x;
    int t = dep[(long)bi * SS + j];
    float r;
    if (t != 0) {
        long gbase = (long)bi * SS + j + (long)b * batchExtra;
        float g = 0.f;
        for (int s = 0; s < nsplit; ++s) g += Gp[gbase + (long)s * splitStride];
        r = g + U[(long)bi * NTP + t] + V[((long)b * SS + j) * NTP + t];
    } else {
        r = NEG;
    }
    float m = r;
    for (int off = 1; off < 64; off <<= 1) m = fmaxf(m, __shfl_xor(m, off));
    __shared__ float smax[2], ssum[2];
    if ((threadIdx.x & 63) == 0) smax[threadIdx.x >> 6] = m;
    __syncthreads();
    m = fmaxf(smax[0], smax[1]);
    float p = expf(r - m);
    float s = p;
    for (int off = 1; off < 64; off <<= 1) s += __shfl_xor(s, off);
    if ((threadIdx.x & 63) == 0) ssum[threadIdx.x >> 6] = s;
    __syncthreads();
    s = ssum[0] + ssum[1];
    float v = p / s;
    if (HILO) {
        Ahi[(long)bi * SS + j] = f2bf(v);
    } else {
        Af[(long)bi * SS + j] = v;
    }
}

// ===========================================================================
// Legacy fp32 path (ws-size fallback) — verified in rounds 1-3.
__device__ __forceinline__ void gemm_body(
    const float* __restrict__ Ab, const float* __restrict__ Bb,
    const float* __restrict__ bias, float* __restrict__ Cb,
    int kbeg, int kend, int lda, int ldb, int ldc,
    int row0, int col0, bool relu) {
    __shared__ float As[16][68];
    __shared__ float Bs[16][68];
    int tx = threadIdx.x & 15, ty = threadIdx.x >> 4;
    float acc[4][4] = {};
    for (int k0 = kbeg; k0 < kend; k0 += 16) {
#pragma unroll
        for (int l = 0; l < 4; ++l) {
            int idx = threadIdx.x + l * 256;
            int r = idx >> 4, kk = idx & 15;
            As[kk][r] = Ab[(long)(row0 + r) * lda + k0 + kk];
            int kk2 = idx >> 6, cc = idx & 63;
            Bs[kk2][cc] = Bb[(long)(k0 + kk2) * ldb + col0 + cc];
        }
        __syncthreads();
#pragma unroll
        for (int kk = 0; kk < 16; ++kk) {
            float4 a4 = *(const float4*)&As[kk][ty * 4];
            float4 b4 = *(const float4*)&Bs[kk][tx * 4];
            float a[4] = {a4.x, a4.y, a4.z, a4.w};
            float b[4] = {b4.x, b4.y, b4.z, b4.w};
#pragma unroll
            for (int i = 0; i < 4; ++i)
#pragma unroll
                for (int j = 0; j < 4; ++j) acc[i][j] += a[i] * b[j];
        }
        __syncthreads();
    }
#pragma unroll
    for (int i = 0; i < 4; ++i) {
        int r = row0 + ty * 4 + i;
#pragma unroll
        for (int j = 0; j < 4; ++j) {
            int c = col0 + tx * 4 + j;
            float v = acc[i][j];
            if (bias) v += bias[c];
            if (relu) v = fmaxf(v, 0.f);
            Cb[(long)r * ldc + c] = v;
        }
    }
}

__global__ __launch_bounds__(256) void gemm_k(
    const float* __restrict__ A, const float* __restrict__ B,
    const float* __restrict__ bias, float* __restrict__ C,
    int K, int nsplit, int lda, int ldb, int ldc,
    long sA, long sB, long sC, long splitStride, int relu) {
    int batch = blockIdx.z / nsplit, split = blockIdx.z % nsplit;
    int kc = K / nsplit;
    const float* Ab = A + (long)batch * sA;
    const float* Bb = B + (long)batch * sB;
    float* Cb = C + (long)batch * sC + (long)split * splitStride;
    gemm_body(Ab, Bb, nsplit == 1 ? bias : nullptr, Cb,
              split * kc, split * kc + kc, lda, ldb, ldc,
              blockIdx.y * 64, blockIdx.x * 64, relu && nsplit == 1);
}

__global__ __launch_bounds__(256) void gram32(
    const float* __restrict__ P1, const float* __restrict__ P2,
    float* __restrict__ Gp) {
    int b = blockIdx.z;
    int i0 = blockIdx.y * 32, j0 = blockIdx.x * 32;
    __shared__ float As[32][33];
    __shared__ float Bs[32][33];
    const float* p1 = P1 + (long)b * SS * DSZ;
    const float* p2 = P2 + (long)b * SS * DSZ;
    int tx = threadIdx.x % 32, ty = threadIdx.x / 32;
    float acc[4] = {0.f, 0.f, 0.f, 0.f};
    for (int k0 = 0; k0 < DSZ; k0 += 32) {
#pragma unroll
        for (int l = 0; l < 4; ++l) {
            int idx = threadIdx.x + l * 256;
            int r = idx / 32, kk = idx % 32;
            As[kk][r] = p1[(long)(i0 + r) * DSZ + k0 + kk];
            Bs[kk][r] = p2[(long)(j0 + r) * DSZ + k0 + kk];
        }
        __syncthreads();
#pragma unroll
        for (int kk = 0; kk < 32; ++kk) {
            float bv = Bs[kk][tx];
#pragma unroll
            for (int i = 0; i < 4; ++i) acc[i] += As[kk][ty * 4 + i] * bv;
        }
        __syncthreads();
    }
#pragma unroll
    for (int i = 0; i < 4; ++i)
        Gp[((long)b * SS + i0 + ty * 4 + i) * SS + j0 + tx] = acc[i];
}

__global__ __launch_bounds__(256) void uv_kernel(
    const float* __restrict__ P1, const float* __restrict__ P2,
    const float* __restrict__ E1, const float* __restrict__ E2,
    const float* __restrict__ cv, float* __restrict__ U, float* __restrict__ V) {
    int bs = blockIdx.x;
    __shared__ float p1[DSZ], p2[DSZ];
    for (int e = threadIdx.x; e < DSZ; e += 256) {
        p1[e] = P1[(long)bs * DSZ + e];
        p2[e] = P2[(long)bs * DSZ + e];
    }
    __syncthreads();
    int wave = threadIdx.x / 64, lane = threadIdx.x % 64;
    for (int t = wave; t < NT; t += 4) {
        float su = 0.f, sv = 0.f;
        for (int e = lane; e < DSZ; e += 64) {
            su += p1[e] * E2[(long)t * DSZ + e];
            sv += p2[e] * E1[(long)t * DSZ + e];
        }
        for (int off = 32; off >= 1; off >>= 1) {
            su += __shfl_down(su, off);
            sv += __shfl_down(sv, off);
        }
        if (lane == 0) {
            U[(long)bs * NTP + t] = su;
            V[(long)bs * NTP + t] = sv + cv[t];
        }
    }
}

// ---------------------------------------------------------------------------
extern "C" void kernel_launch(void* const* d_in, const int* in_sizes, int n_in,
                              void* d_out, int out_size, void* d_ws, size_t ws_size,
                              hipStream_t stream) {
    const float* h      = (const float*)d_in[0];
    const int*   dep    = (const int*)d_in[1];
    const float* table  = (const float*)d_in[2];
    const float* W1_w   = (const float*)d_in[3];
    const float* W1_b   = (const float*)d_in[4];
    const float* W2_w   = (const float*)d_in[5];
    const float* W2_b   = (const float*)d_in[6];
    const float* gcn_w  = (const float*)d_in[7];
    const float* gcn_b  = (const float*)d_in[8];
    const float* Wo_w   = (const float*)d_in[9];
    const float* Wo_b   = (const float*)d_in[10];
    float* out = (float*)d_out;

    const long nBS = (long)BB * SS;        // 1024
    const long MN  = nBS * DSZ;            // 786432
    const long BSS = (long)BB * SS * SS;   // 131072
    const long UVN = nBS * NTP;            // 49152
    const long EN  = (long)NTP * DSZ;      // 36864
    const long WN  = (long)DSZ * HID;      // 589824
    const long BSD = (long)SS * DSZ;       // 98304

    char* base = (char*)d_ws;
    size_t off = 0;
    auto alloc = [&](size_t bytes) -> void* {
        void* p = base + off;
        off += (bytes + 255) & ~(size_t)255;
        return p;
    };

    float* Ef    = (float*)alloc(2 * EN * 4);
    float* CV    = (float*)alloc(256);
    float* U     = (float*)alloc(UVN * 4);
    float* V     = (float*)alloc(UVN * 4);
    float* PART  = (float*)alloc(8 * MN * 4);   // shared by all partial stages
    unsigned short* EtHi = (unsigned short*)alloc(2 * EN * 2);
    unsigned short* EtLo = (unsigned short*)alloc(2 * EN * 2);
    unsigned short* hHi  = (unsigned short*)alloc(MN * 2);
    unsigned short* hLo  = (unsigned short*)alloc(MN * 2);
    unsigned short* htHi = (unsigned short*)alloc(MN * 2);
    unsigned short* WtHi = (unsigned short*)alloc(2 * WN * 2);
    unsigned short* WtLo = (unsigned short*)alloc(2 * WN * 2);
    unsigned short* gTHi = (unsigned short*)alloc(WN * 2);
    unsigned short* oTHi = (unsigned short*)alloc(WN * 2);
    unsigned short* Phi  = (unsigned short*)alloc(2 * MN * 2);
    unsigned short* Plo  = (unsigned short*)alloc(2 * MN * 2);
    unsigned short* AmHi = (unsigned short*)alloc(BSS * 2);
    unsigned short* AGHi = (unsigned short*)alloc(MN * 2);
    unsigned short* HSHi = (unsigned short*)alloc(MN * 2);
    size_t needBig = off;

    if (ws_size >= needBig) {
        e_kernel<<<(NTP * DSZ + 255) / 256, 256, 0, stream>>>(table, W1_w, W2_w, Ef, EtHi, EtLo);
        c_kernel<<<NT, 256, 0, stream>>>(Ef, CV);

        // conversions
        conv_hilo<<<(MN / 4 + 255) / 256, 256, 0, stream>>>(h, hHi, hLo, MN);
        conv_T<0><<<dim3(HID / 32, SS / 32, BB), 256, 0, stream>>>(h, HID, BSD, htHi, nullptr, SS, BSD);
        conv_T<1><<<dim3(DSZ / 32, HID / 32, 1), 256, 0, stream>>>(W1_w, DSZ, 0, WtHi, WtLo, HID, 0);
        conv_T<1><<<dim3(DSZ / 32, HID / 32, 1), 256, 0, stream>>>(W2_w, DSZ, 0, WtHi + WN, WtLo + WN, HID, 0);
        conv_T<0><<<dim3(HID / 32, HID / 32, 1), 256, 0, stream>>>(gcn_w, HID, 0, gTHi, nullptr, HID, 0);
        conv_T<0><<<dim3(HID / 32, DSZ / 32, 1), 256, 0, stream>>>(Wo_w, HID, 0, oTHi, nullptr, DSZ, 0);

        // P1/P2 = h @ {W1,W2}[:HID] + b   (dual via batch, split-K=4 -> 384 blk)
        mfma_gemm<3, 0><<<dim3(6, 8, 8), 256, 0, stream>>>(
            hHi, hLo, WtHi, WtLo, PART, nullptr, nullptr, 0,
            HID, 4, DSZ, DSZ, 0, WN, 4 * MN, MN);
        reduce_k2<1><<<(MN / 4 + 255) / 256, 256, 0, stream>>>(
            PART, MN, 4, W1_b, DSZ, nullptr, Phi, Plo, MN, 0);
        reduce_k2<1><<<(MN / 4 + 255) / 256, 256, 0, stream>>>(
            PART + 4 * MN, MN, 4, W2_b, DSZ, nullptr, Phi + MN, Plo + MN, MN, 0);

        // U = P1@E2^T, V = P2@E1^T (+c)   split-K=4 -> 64 blk
        mfma_gemm<3, 0><<<dim3(1, 8, 8), 256, 0, stream>>>(
            Phi, Plo, EtHi, EtLo, PART, nullptr, nullptr, 0,
            DSZ, 4, NTP, NTP, MN, EN, 4 * UVN, UVN);
        uv_reduce<<<(UVN + 255) / 256, 256, 0, stream>>>(PART, CV, U, V, 4);

        // G[b] = P1_b @ P2_b^T   split-K=8 -> 64 blk, partials [b][s][128*128]
        mfma_gemm<3, 0><<<dim3(1, 1, 64), 256, 0, stream>>>(
            Phi, Plo, Phi + MN, Plo + MN, PART, nullptr, nullptr, 0,
            DSZ, 8, SS, SS, BSD, BSD, 8 * (long)SS * SS, (long)SS * SS);
        softmax_kernel<1><<<nBS, 128, 0, stream>>>(
            dep, PART, 8, (long)SS * SS, 7L * SS * SS, U, V, nullptr, AmHi, nullptr);

        // AGG = A @ h (batched, K=128), bf16 out fused -> 48 blk, no reduce
        mfma_gemm<1, 1><<<dim3(6, 1, 8), 256, 0, stream>>>(
            AmHi, nullptr, htHi, nullptr, nullptr, AGHi, nullptr, 0,
            SS, 1, HID, HID, (long)SS * SS, BSD, BSD, 0);

        // HSYN = relu(AGG @ gcn + b)   split-K=4 -> 192 blk
        mfma_gemm<1, 0><<<dim3(6, 8, 4), 256, 0, stream>>>(
            AGHi, nullptr, gTHi, nullptr, PART, nullptr, nullptr, 0,
            HID, 4, HID, HID, 0, 0, 0, MN);
        reduce_k2<2><<<(MN / 4 + 255) / 256, 256, 0, stream>>>(
            PART, MN, 4, gcn_b, HID, nullptr, HSHi, nullptr, MN, 1);

        // out = HSYN @ Wo + b   split-K=4 -> 192 blk
        mfma_gemm<1, 0><<<dim3(6, 8, 4), 256, 0, stream>>>(
            HSHi, nullptr, oTHi, nullptr, PART, nullptr, nullptr, 0,
            DSZ, 4, HID, HID, 0, 0, 0, MN);
        reduce_k2<0><<<(MN / 4 + 255) / 256, 256, 0, stream>>>(
            PART, MN, 4, Wo_b, HID, out, nullptr, nullptr, MN, 0);
    } else {
        // Fallback: verified fp32 nsplit=1 path, compact layout.
        float* ws = (float*)d_ws;
        long o2 = 0;
        float* Ef2  = ws + o2; o2 += 2 * EN;
        float* CV2  = ws + o2; o2 += 64;
        float* P1   = ws + o2; o2 += MN;
        float* P2   = ws + o2; o2 += MN;
        float* Uf   = ws + o2; o2 += UVN;
        float* Vf   = ws + o2; o2 += UVN;
        float* G    = ws + o2; o2 += BSS;
        float* Amat = ws + o2; o2 += BSS;
        float* AGG  = ws + o2; o2 += MN;
        float* HSYN = ws + o2; o2 += MN;
        unsigned short* Eh2 = (unsigned short*)(ws + o2); o2 += EN;
        unsigned short* El2 = (unsigned short*)(ws + o2); o2 += EN;

        e_kernel<<<(NTP * DSZ + 255) / 256, 256, 0, stream>>>(table, W1_w, W2_w, Ef2, Eh2, El2);
        c_kernel<<<NT, 256, 0, stream>>>(Ef2, CV2);
        gemm_k<<<dim3(DSZ / 64, nBS / 64, 1), 256, 0, stream>>>(
            h, W1_w, W1_b, P1, HID, 1, HID, DSZ, DSZ, 0, 0, 0, 0, 0);
        gemm_k<<<dim3(DSZ / 64, nBS / 64, 1), 256, 0, stream>>>(
            h, W2_w, W2_b, P2, HID, 1, HID, DSZ, DSZ, 0, 0, 0, 0, 0);
        uv_kernel<<<nBS, 256, 0, stream>>>(P1, P2, Ef2 + EN, Ef2, CV2, Uf, Vf);
        gram32<<<dim3(SS / 32, SS / 32, BB), 256, 0, stream>>>(P1, P2, G);
        softmax_kernel<0><<<nBS, 128, 0, stream>>>(dep, G, 1, BSS, 0, Uf, Vf, Amat, nullptr, nullptr);
        gemm_k<<<dim3(HID / 64, SS / 64, BB), 256, 0, stream>>>(
            Amat, h, nullptr, AGG, SS, 1, SS, HID, HID,
            (long)SS * SS, BSD, BSD, 0, 0);
        gemm_k<<<dim3(HID / 64, nBS / 64, 1), 256, 0, stream>>>(
            AGG, gcn_w, gcn_b, HSYN, HID, 1, HID, HID, HID, 0, 0, 0, 0, 1);
        gemm_k<<<dim3(HID / 64, nBS / 64, 1), 256, 0, stream>>>(
            HSYN, Wo_w, Wo_b, out, DSZ, 1, DSZ, HID, HID, 0, 0, 0, 0, 0);
    }
}

// Round 7
// 107.486 us; speedup vs baseline: 3.3030x; 1.0783x over previous
//
#include <hip/hip_runtime.h>
#include <hip/hip_bf16.h>

#define BB 8
#define SS 128
#define HID 768
#define DEP 64
#define DSZ 768
#define NT 45
#define NTP 48
#define NEG -1000000000.0f

typedef short bfv8 __attribute__((ext_vector_type(8)));
typedef float f32x4 __attribute__((ext_vector_type(4)));

__device__ __forceinline__ unsigned short f2bf(float x) {
    unsigned int u; __builtin_memcpy(&u, &x, 4);
    u += 0x7fffu + ((u >> 16) & 1u);
    return (unsigned short)(u >> 16);
}
__device__ __forceinline__ float bf2f(unsigned short h) {
    unsigned int u = ((unsigned int)h) << 16;
    float f; __builtin_memcpy(&f, &u, 4);
    return f;
}

// async global->LDS, 16B per lane. LDS dest must be wave-uniform base;
// HW writes base + lane*16 (CK-style addrspace casts).
__device__ __forceinline__ void gld16(const unsigned short* gp, unsigned short* lp) {
    typedef __attribute__((address_space(1))) const unsigned int GU;
    typedef __attribute__((address_space(3))) unsigned int LU;
    __builtin_amdgcn_global_load_lds((GU*)(uintptr_t)gp,
                                     (LU*)(unsigned int)(uintptr_t)lp, 16, 0, 0);
}

// ---------------------------------------------------------------------------
// E: slot0 = E2 = table @ W2[HID:], slot1 = E1 = table @ W1[HID:].
__global__ void e_kernel(const float* __restrict__ table,
                         const float* __restrict__ W1,
                         const float* __restrict__ W2,
                         float* __restrict__ Ef,
                         unsigned short* __restrict__ Ehi,
                         unsigned short* __restrict__ Elo) {
    int idx = blockIdx.x * blockDim.x + threadIdx.x;
    if (idx >= NTP * DSZ) return;
    int t = idx / DSZ, e = idx % DSZ;
    float s1 = 0.f, s2 = 0.f;
    if (t < NT)
        for (int d = 0; d < DEP; ++d) {
            float td = table[t * DEP + d];
            s1 += td * W1[(HID + d) * DSZ + e];
            s2 += td * W2[(HID + d) * DSZ + e];
        }
    const long EN = (long)NTP * DSZ;
    Ef[idx] = s2; Ef[EN + idx] = s1;
    unsigned short h2 = f2bf(s2), h1 = f2bf(s1);
    Ehi[idx] = h2;      Elo[idx] = f2bf(s2 - bf2f(h2));
    Ehi[EN + idx] = h1; Elo[EN + idx] = f2bf(s1 - bf2f(h1));
}

// c[t] = dot(E1[t,:], E2[t,:])
__global__ void c_kernel(const float* __restrict__ Ef, float* __restrict__ cv) {
    int t = blockIdx.x;
    const long EN = (long)NTP * DSZ;
    float s = 0.f;
    for (int e = threadIdx.x; e < DSZ; e += 256)
        s += Ef[(long)t * DSZ + e] * Ef[EN + (long)t * DSZ + e];
    __shared__ float red[256];
    red[threadIdx.x] = s;
    __syncthreads();
    for (int w = 128; w >= 1; w >>= 1) {
        if (threadIdx.x < w) red[threadIdx.x] += red[threadIdx.x + w];
        __syncthreads();
    }
    if (threadIdx.x == 0) cv[t] = red[0];
}

// ---------------------------------------------------------------------------
// h: straight hi/lo ([S][HID], for P-GEMM A) + transposed hi ([HID][S]/batch,
// for AGG B) in one pass.  Grid (HID/32, SS/32, BB).
__global__ __launch_bounds__(256) void conv_h(
    const float* __restrict__ h, unsigned short* __restrict__ hHi,
    unsigned short* __restrict__ hLo, unsigned short* __restrict__ htHi) {
    int b = blockIdx.z;
    int r0 = blockIdx.y * 32, c0 = blockIdx.x * 32;
    __shared__ float tile[32][33];
    const float* Xb = h + (long)b * SS * HID;
    int tr = threadIdx.x >> 5, tc = threadIdx.x & 31;
#pragma unroll
    for (int k = 0; k < 4; ++k) {
        int rr = r0 + tr + k * 8, cc = c0 + tc;
        float v = Xb[(long)rr * HID + cc];
        tile[tr + k * 8][tc] = v;
        unsigned short hh = f2bf(v);
        long o = (long)b * SS * HID + (long)rr * HID + cc;
        hHi[o] = hh;
        hLo[o] = f2bf(v - bf2f(hh));
    }
    __syncthreads();
#pragma unroll
    for (int k = 0; k < 4; ++k) {
        int i = tr + k * 8, j = tc;
        float v = tile[j][i];  // = X[r0+j][c0+i]
        long o = (long)b * (SS * HID) + (long)(c0 + i) * SS + (r0 + j);
        htHi[o] = f2bf(v);
    }
}

// All four 768x768 weights transposed+converted in one launch (z selects).
// lo written only for W1/W2 (logit path).  Grid (24, 24, 4).
__global__ __launch_bounds__(256) void conv_T4(
    const float* __restrict__ W1, const float* __restrict__ W2,
    const float* __restrict__ gcn, const float* __restrict__ Wo,
    unsigned short* __restrict__ WtHi, unsigned short* __restrict__ WtLo,
    unsigned short* __restrict__ gTHi, unsigned short* __restrict__ oTHi) {
    const long WN = (long)DSZ * HID;
    int which = blockIdx.z;
    const float* src = which == 0 ? W1 : which == 1 ? W2 : which == 2 ? gcn : Wo;
    unsigned short* dhi = which == 0 ? WtHi : which == 1 ? WtHi + WN
                        : which == 2 ? gTHi : oTHi;
    unsigned short* dlo = which == 0 ? WtLo : which == 1 ? WtLo + WN : nullptr;
    int r0 = blockIdx.y * 32, c0 = blockIdx.x * 32;
    __shared__ float tile[32][33];
    int tr = threadIdx.x >> 5, tc = threadIdx.x & 31;
#pragma unroll
    for (int k = 0; k < 4; ++k)
        tile[tr + k * 8][tc] = src[(long)(r0 + tr + k * 8) * 768 + c0 + tc];
    __syncthreads();
#pragma unroll
    for (int k = 0; k < 4; ++k) {
        int i = tr + k * 8, j = tc;
        float v = tile[j][i];
        unsigned short hh = f2bf(v);
        long o = (long)(c0 + i) * 768 + r0 + j;
        dhi[o] = hh;
        if (dlo) dlo[o] = f2bf(v - bf2f(hh));
    }
}

// ---------------------------------------------------------------------------
// bf16 MFMA GEMM: C = A @ Bt^T  (A [M][K], Bt [N][K]).
// PREC==3: split-precision hi/lo, D = Ahi*Bhi + Ahi*Blo + Alo*Bhi (~2^-17).
// PREC==1: plain bf16 (hi only).
// OUT==0: fp32 C (partials).  OUT==1: bf16 Cb direct, bias+relu (nsplit==1).
// Tile 128x128, BK=32, 256 threads = 4 waves (2x2), 4x4 16x16x32 frags/wave.
// Staging via global_load_lds: seg s=tid covers LDS bytes [16s,16s+16),
// wave-uniform dest base + per-lane global address.
template <int PREC, int OUT>
__global__ __launch_bounds__(256) void mfma_gemm(
    const unsigned short* __restrict__ Ahi, const unsigned short* __restrict__ Alo,
    const unsigned short* __restrict__ Bhi, const unsigned short* __restrict__ Blo,
    float* __restrict__ C, unsigned short* __restrict__ Cb16,
    const float* __restrict__ bias, int relu,
    int K, int nsplit, int ldc, int Nvalid,
    long sA, long sB, long sC, long splitStride) {
    int batch = blockIdx.z / nsplit, split = blockIdx.z - batch * nsplit;
    int kc = K / nsplit;
    int kb = split * kc;
    const unsigned short* ah = Ahi + (long)batch * sA;
    const unsigned short* bh = Bhi + (long)batch * sB;
    int m0 = blockIdx.y * 128, n0 = blockIdx.x * 128;

    __shared__ __align__(16) unsigned short sAh[4096], sBh[4096];
    __shared__ __align__(16) unsigned short sAl[PREC == 3 ? 4096 : 16];
    __shared__ __align__(16) unsigned short sBl[PREC == 3 ? 4096 : 16];
    int tid = threadIdx.x;
    int lane = tid & 63, wave = tid >> 6;
    int wr = wave >> 1, wc = wave & 1;
    int q = lane >> 4, r = lane & 15;

    f32x4 acc[4][4];
#pragma unroll
    for (int i = 0; i < 4; ++i)
#pragma unroll
        for (int j = 0; j < 4; ++j) acc[i][j] = (f32x4){0.f, 0.f, 0.f, 0.f};

    // seg s: row = s>>2, kseg = s&3; bytes 16s. Wave w owns segs [64w,64w+64).
    int s0 = tid, s1 = tid + 256;
    int arow0 = s0 >> 2, ak0 = (s0 & 3) << 3;
    int arow1 = s1 >> 2, ak1 = (s1 & 3) << 3;
    const unsigned short* aP0 = ah + (long)(m0 + arow0) * K + ak0;
    const unsigned short* aP1 = ah + (long)(m0 + arow1) * K + ak1;
    bool bok0 = (n0 + arow0) < Nvalid, bok1 = (n0 + arow1) < Nvalid;
    const unsigned short* bP0 = bh + (long)(n0 + arow0) * K + ak0;
    const unsigned short* bP1 = bh + (long)(n0 + arow1) * K + ak1;
    const unsigned short* alP0 = nullptr; const unsigned short* alP1 = nullptr;
    const unsigned short* blP0 = nullptr; const unsigned short* blP1 = nullptr;
    if constexpr (PREC == 3) {
        const unsigned short* al = Alo + (long)batch * sA;
        const unsigned short* bl = Blo + (long)batch * sB;
        alP0 = al + (long)(m0 + arow0) * K + ak0;
        alP1 = al + (long)(m0 + arow1) * K + ak1;
        blP0 = bl + (long)(n0 + arow0) * K + ak0;
        blP1 = bl + (long)(n0 + arow1) * K + ak1;
    }
    // wave-uniform LDS dest bases (bytes 1024*wave and 4096+1024*wave)
    unsigned short* lA0 = sAh + (wave << 9);
    unsigned short* lA1 = sAh + 2048 + (wave << 9);
    unsigned short* lB0 = sBh + (wave << 9);
    unsigned short* lB1 = sBh + 2048 + (wave << 9);
    unsigned short* lAl0 = sAl + (wave << 9);
    unsigned short* lAl1 = sAl + 2048 + (wave << 9);
    unsigned short* lBl0 = sBl + (wave << 9);
    unsigned short* lBl1 = sBl + 2048 + (wave << 9);

    int aOff[4], bOff[4];
#pragma unroll
    for (int f = 0; f < 4; ++f) {
        aOff[f] = (wr * 64 + f * 16 + r) * 32 + q * 8;
        bOff[f] = (wc * 64 + f * 16 + r) * 32 + q * 8;
    }

    for (int k0 = kb; k0 < kb + kc; k0 += 32) {
        __syncthreads();  // previous compute done before overwrite
        gld16(aP0 + k0, lA0);
        gld16(aP1 + k0, lA1);
        if (bok0) gld16(bP0 + k0, lB0);
        if (bok1) gld16(bP1 + k0, lB1);
        if constexpr (PREC == 3) {
            gld16(alP0 + k0, lAl0);
            gld16(alP1 + k0, lAl1);
            if (bok0) gld16(blP0 + k0, lBl0);
            if (bok1) gld16(blP1 + k0, lBl1);
        }
        __syncthreads();  // compiler drains vmcnt(0) before barrier

        bfv8 bh_r[4], bl_r[4];
#pragma unroll
        for (int fc = 0; fc < 4; ++fc) {
            bh_r[fc] = *(const bfv8*)(sBh + bOff[fc]);
            if constexpr (PREC == 3) bl_r[fc] = *(const bfv8*)(sBl + bOff[fc]);
        }
#pragma unroll
        for (int fr = 0; fr < 4; ++fr) {
            bfv8 a_h = *(const bfv8*)(sAh + aOff[fr]);
            bfv8 a_l;
            if constexpr (PREC == 3) a_l = *(const bfv8*)(sAl + aOff[fr]);
#pragma unroll
            for (int fc = 0; fc < 4; ++fc) {
                acc[fr][fc] = __builtin_amdgcn_mfma_f32_16x16x32_bf16(a_h, bh_r[fc], acc[fr][fc], 0, 0, 0);
                if constexpr (PREC == 3) {
                    acc[fr][fc] = __builtin_amdgcn_mfma_f32_16x16x32_bf16(a_h, bl_r[fc], acc[fr][fc], 0, 0, 0);
                    acc[fr][fc] = __builtin_amdgcn_mfma_f32_16x16x32_bf16(a_l, bh_r[fc], acc[fr][fc], 0, 0, 0);
                }
            }
        }
    }
    if constexpr (OUT == 0) {
        float* Cb = C + (long)batch * sC + (long)split * splitStride;
#pragma unroll
        for (int fr = 0; fr < 4; ++fr) {
            int rr = m0 + wr * 64 + fr * 16 + q * 4;
#pragma unroll
            for (int fc = 0; fc < 4; ++fc) {
                int cc = n0 + wc * 64 + fc * 16 + r;
                if (cc < Nvalid) {
#pragma unroll
                    for (int i = 0; i < 4; ++i)
                        Cb[(long)(rr + i) * ldc + cc] = acc[fr][fc][i];
                }
            }
        }
    } else {
        unsigned short* Cb = Cb16 + (long)batch * sC;
#pragma unroll
        for (int fr = 0; fr < 4; ++fr) {
            int rr = m0 + wr * 64 + fr * 16 + q * 4;
#pragma unroll
            for (int fc = 0; fc < 4; ++fc) {
                int cc = n0 + wc * 64 + fc * 16 + r;
                if (cc < Nvalid) {
                    float bv = bias ? bias[cc] : 0.f;
#pragma unroll
                    for (int i = 0; i < 4; ++i) {
                        float v = acc[fr][fc][i] + bv;
                        if (relu) v = fmaxf(v, 0.f);
                        Cb[(long)(rr + i) * ldc + cc] = f2bf(v);
                    }
                }
            }
        }
    }
}

// ---------------------------------------------------------------------------
// sum split partials (+bias)(+relu).  HILO: 0=fp32 out, 1=hi+lo, 2=hi only.
template <int HILO>
__global__ __launch_bounds__(256) void reduce_k2(
    const float* __restrict__ part, long splitStride, int nsplit,
    const float* __restrict__ bias, int ldc, float* __restrict__ outf,
    unsigned short* __restrict__ ohi, unsigned short* __restrict__ olo,
    long n, int relu) {
    long i = (long)blockIdx.x * 256 + threadIdx.x;
    if (i * 4 >= n) return;
    float4 s = ((const float4*)part)[i];
    for (int p = 1; p < nsplit; ++p) {
        float4 t = ((const float4*)(part + (long)p * splitStride))[i];
        s.x += t.x; s.y += t.y; s.z += t.z; s.w += t.w;
    }
    if (bias) {
        long col = (i * 4) % ldc;
        s.x += bias[col]; s.y += bias[col + 1];
        s.z += bias[col + 2]; s.w += bias[col + 3];
    }
    if (relu) {
        s.x = fmaxf(s.x, 0.f); s.y = fmaxf(s.y, 0.f);
        s.z = fmaxf(s.z, 0.f); s.w = fmaxf(s.w, 0.f);
    }
    if (HILO == 0) {
        ((float4*)outf)[i] = s;
    } else {
        ushort4 h;
        h.x = f2bf(s.x); h.y = f2bf(s.y); h.z = f2bf(s.z); h.w = f2bf(s.w);
        ((ushort4*)ohi)[i] = h;
        if (HILO == 1) {
            ushort4 l;
            l.x = f2bf(s.x - bf2f(h.x)); l.y = f2bf(s.y - bf2f(h.y));
            l.z = f2bf(s.z - bf2f(h.z)); l.w = f2bf(s.w - bf2f(h.w));
            ((ushort4*)olo)[i] = l;
        }
    }
}

// U/V partial reduce: Up z-order = which(U=0,V=1)*nsplit + split, each 1024*48.
__global__ __launch_bounds__(256) void uv_reduce(
    const float* __restrict__ Up, const float* __restrict__ cv,
    float* __restrict__ U, float* __restrict__ V, int nsplit) {
    const long n = (long)BB * SS * NTP;
    long idx = (long)blockIdx.x * 256 + threadIdx.x;
    if (idx >= n) return;
    int t = idx % NTP;
    float su = 0.f, sv = 0.f;
    for (int s = 0; s < nsplit; ++s) {
        su += Up[(long)s * n + idx];
        sv += Up[((long)nsplit + s) * n + idx];
    }
    U[idx] = su;
    V[idx] = sv + (t < NT ? cv[t] : 0.f);
}

// ---------------------------------------------------------------------------
// relevance (sum split partials of G) + mask + softmax over j.
template <int HILO>
__global__ __launch_bounds__(128) void softmax_kernel(
    const int* __restrict__ dep, const float* __restrict__ Gp, int nsplit,
    long splitStride, long batchExtra,
    const float* __restrict__ U, const float* __restrict__ V,
    float* __restrict__ Af, unsigned short* __restrict__ Ahi,
    unsigned short* __restrict__ Alo) {
    int bi = blockIdx.x;
    int b = bi >> 7;
    int j = threadIdx.x;
    int t = dep[(long)bi * SS + j];
    float r;
    if (t != 0) {
        long gbase = (long)bi * SS + j + (long)b * batchExtra;
        float g = 0.f;
        for (int s = 0; s < nsplit; ++s) g += Gp[gbase + (long)s * splitStride];
        r = g + U[(long)bi * NTP + t] + V[((long)b * SS + j) * NTP + t];
    } else {
        r = NEG;
    }
    float m = r;
    for (int off = 1; off < 64; off <<= 1) m = fmaxf(m, __shfl_xor(m, off));
    __shared__ float smax[2], ssum[2];
    if ((threadIdx.x & 63) == 0) smax[threadIdx.x >> 6] = m;
    __syncthreads();
    m = fmaxf(smax[0], smax[1]);
    float p = expf(r - m);
    float s = p;
    for (int off = 1; off < 64; off <<= 1) s += __shfl_xor(s, off);
    if ((threadIdx.x & 63) == 0) ssum[threadIdx.x >> 6] = s;
    __syncthreads();
    s = ssum[0] + ssum[1];
    float v = p / s;
    if (HILO) {
        Ahi[(long)bi * SS + j] = f2bf(v);
    } else {
        Af[(long)bi * SS + j] = v;
    }
}

// ===========================================================================
// Legacy fp32 path (ws-size fallback) — verified in rounds 1-3.
__device__ __forceinline__ void gemm_body(
    const float* __restrict__ Ab, const float* __restrict__ Bb,
    const float* __restrict__ bias, float* __restrict__ Cb,
    int kbeg, int kend, int lda, int ldb, int ldc,
    int row0, int col0, bool relu) {
    __shared__ float As[16][68];
    __shared__ float Bs[16][68];
    int tx = threadIdx.x & 15, ty = threadIdx.x >> 4;
    float acc[4][4] = {};
    for (int k0 = kbeg; k0 < kend; k0 += 16) {
#pragma unroll
        for (int l = 0; l < 4; ++l) {
            int idx = threadIdx.x + l * 256;
            int r = idx >> 4, kk = idx & 15;
            As[kk][r] = Ab[(long)(row0 + r) * lda + k0 + kk];
            int kk2 = idx >> 6, cc = idx & 63;
            Bs[kk2][cc] = Bb[(long)(k0 + kk2) * ldb + col0 + cc];
        }
        __syncthreads();
#pragma unroll
        for (int kk = 0; kk < 16; ++kk) {
            float4 a4 = *(const float4*)&As[kk][ty * 4];
            float4 b4 = *(const float4*)&Bs[kk][tx * 4];
            float a[4] = {a4.x, a4.y, a4.z, a4.w};
            float b[4] = {b4.x, b4.y, b4.z, b4.w};
#pragma unroll
            for (int i = 0; i < 4; ++i)
#pragma unroll
                for (int j = 0; j < 4; ++j) acc[i][j] += a[i] * b[j];
        }
        __syncthreads();
    }
#pragma unroll
    for (int i = 0; i < 4; ++i) {
        int r = row0 + ty * 4 + i;
#pragma unroll
        for (int j = 0; j < 4; ++j) {
            int c = col0 + tx * 4 + j;
            float v = acc[i][j];
            if (bias) v += bias[c];
            if (relu) v = fmaxf(v, 0.f);
            Cb[(long)r * ldc + c] = v;
        }
    }
}

__global__ __launch_bounds__(256) void gemm_k(
    const float* __restrict__ A, const float* __restrict__ B,
    const float* __restrict__ bias, float* __restrict__ C,
    int K, int nsplit, int lda, int ldb, int ldc,
    long sA, long sB, long sC, long splitStride, int relu) {
    int batch = blockIdx.z / nsplit, split = blockIdx.z % nsplit;
    int kc = K / nsplit;
    const float* Ab = A + (long)batch * sA;
    const float* Bb = B + (long)batch * sB;
    float* Cb = C + (long)batch * sC + (long)split * splitStride;
    gemm_body(Ab, Bb, nsplit == 1 ? bias : nullptr, Cb,
              split * kc, split * kc + kc, lda, ldb, ldc,
              blockIdx.y * 64, blockIdx.x * 64, relu && nsplit == 1);
}

__global__ __launch_bounds__(256) void gram32(
    const float* __restrict__ P1, const float* __restrict__ P2,
    float* __restrict__ Gp) {
    int b = blockIdx.z;
    int i0 = blockIdx.y * 32, j0 = blockIdx.x * 32;
    __shared__ float As[32][33];
    __shared__ float Bs[32][33];
    const float* p1 = P1 + (long)b * SS * DSZ;
    const float* p2 = P2 + (long)b * SS * DSZ;
    int tx = threadIdx.x % 32, ty = threadIdx.x / 32;
    float acc[4] = {0.f, 0.f, 0.f, 0.f};
    for (int k0 = 0; k0 < DSZ; k0 += 32) {
#pragma unroll
        for (int l = 0; l < 4; ++l) {
            int idx = threadIdx.x + l * 256;
            int r = idx / 32, kk = idx % 32;
            As[kk][r] = p1[(long)(i0 + r) * DSZ + k0 + kk];
            Bs[kk][r] = p2[(long)(j0 + r) * DSZ + k0 + kk];
        }
        __syncthreads();
#pragma unroll
        for (int kk = 0; kk < 32; ++kk) {
            float bv = Bs[kk][tx];
#pragma unroll
            for (int i = 0; i < 4; ++i) acc[i] += As[kk][ty * 4 + i] * bv;
        }
        __syncthreads();
    }
#pragma unroll
    for (int i = 0; i < 4; ++i)
        Gp[((long)b * SS + i0 + ty * 4 + i) * SS + j0 + tx] = acc[i];
}

__global__ __launch_bounds__(256) void uv_kernel(
    const float* __restrict__ P1, const float* __restrict__ P2,
    const float* __restrict__ E1, const float* __restrict__ E2,
    const float* __restrict__ cv, float* __restrict__ U, float* __restrict__ V) {
    int bs = blockIdx.x;
    __shared__ float p1[DSZ], p2[DSZ];
    for (int e = threadIdx.x; e < DSZ; e += 256) {
        p1[e] = P1[(long)bs * DSZ + e];
        p2[e] = P2[(long)bs * DSZ + e];
    }
    __syncthreads();
    int wave = threadIdx.x / 64, lane = threadIdx.x % 64;
    for (int t = wave; t < NT; t += 4) {
        float su = 0.f, sv = 0.f;
        for (int e = lane; e < DSZ; e += 64) {
            su += p1[e] * E2[(long)t * DSZ + e];
            sv += p2[e] * E1[(long)t * DSZ + e];
        }
        for (int off = 32; off >= 1; off >>= 1) {
            su += __shfl_down(su, off);
            sv += __shfl_down(sv, off);
        }
        if (lane == 0) {
            U[(long)bs * NTP + t] = su;
            V[(long)bs * NTP + t] = sv + cv[t];
        }
    }
}

// ---------------------------------------------------------------------------
extern "C" void kernel_launch(void* const* d_in, const int* in_sizes, int n_in,
                              void* d_out, int out_size, void* d_ws, size_t ws_size,
                              hipStream_t stream) {
    const float* h      = (const float*)d_in[0];
    const int*   dep    = (const int*)d_in[1];
    const float* table  = (const float*)d_in[2];
    const float* W1_w   = (const float*)d_in[3];
    const float* W1_b   = (const float*)d_in[4];
    const float* W2_w   = (const float*)d_in[5];
    const float* W2_b   = (const float*)d_in[6];
    const float* gcn_w  = (const float*)d_in[7];
    const float* gcn_b  = (const float*)d_in[8];
    const float* Wo_w   = (const float*)d_in[9];
    const float* Wo_b   = (const float*)d_in[10];
    float* out = (float*)d_out;

    const long nBS = (long)BB * SS;        // 1024
    const long MN  = nBS * DSZ;            // 786432
    const long BSS = (long)BB * SS * SS;   // 131072
    const long UVN = nBS * NTP;            // 49152
    const long EN  = (long)NTP * DSZ;      // 36864
    const long WN  = (long)DSZ * HID;      // 589824
    const long BSD = (long)SS * DSZ;       // 98304

    char* base = (char*)d_ws;
    size_t off = 0;
    auto alloc = [&](size_t bytes) -> void* {
        void* p = base + off;
        off += (bytes + 255) & ~(size_t)255;
        return p;
    };

    float* Ef    = (float*)alloc(2 * EN * 4);
    float* CV    = (float*)alloc(256);
    float* U     = (float*)alloc(UVN * 4);
    float* V     = (float*)alloc(UVN * 4);
    float* PART  = (float*)alloc(8 * MN * 4);   // shared by all partial stages
    unsigned short* EtHi = (unsigned short*)alloc(2 * EN * 2);
    unsigned short* EtLo = (unsigned short*)alloc(2 * EN * 2);
    unsigned short* hHi  = (unsigned short*)alloc(MN * 2);
    unsigned short* hLo  = (unsigned short*)alloc(MN * 2);
    unsigned short* htHi = (unsigned short*)alloc(MN * 2);
    unsigned short* WtHi = (unsigned short*)alloc(2 * WN * 2);
    unsigned short* WtLo = (unsigned short*)alloc(2 * WN * 2);
    unsigned short* gTHi = (unsigned short*)alloc(WN * 2);
    unsigned short* oTHi = (unsigned short*)alloc(WN * 2);
    unsigned short* Phi  = (unsigned short*)alloc(2 * MN * 2);
    unsigned short* Plo  = (unsigned short*)alloc(2 * MN * 2);
    unsigned short* AmHi = (unsigned short*)alloc(BSS * 2);
    unsigned short* AGHi = (unsigned short*)alloc(MN * 2);
    unsigned short* HSHi = (unsigned short*)alloc(MN * 2);
    size_t needBig = off;

    if (ws_size >= needBig) {
        e_kernel<<<(NTP * DSZ + 255) / 256, 256, 0, stream>>>(table, W1_w, W2_w, Ef, EtHi, EtLo);
        c_kernel<<<NT, 256, 0, stream>>>(Ef, CV);

        // conversions (2 launches)
        conv_h<<<dim3(HID / 32, SS / 32, BB), 256, 0, stream>>>(h, hHi, hLo, htHi);
        conv_T4<<<dim3(24, 24, 4), 256, 0, stream>>>(
            W1_w, W2_w, gcn_w, Wo_w, WtHi, WtLo, gTHi, oTHi);

        // P1/P2 = h @ {W1,W2}[:HID] + b   (dual via batch, split-K=4 -> 384 blk)
        mfma_gemm<3, 0><<<dim3(6, 8, 8), 256, 0, stream>>>(
            hHi, hLo, WtHi, WtLo, PART, nullptr, nullptr, 0,
            HID, 4, DSZ, DSZ, 0, WN, 4 * MN, MN);
        reduce_k2<1><<<(MN / 4 + 255) / 256, 256, 0, stream>>>(
            PART, MN, 4, W1_b, DSZ, nullptr, Phi, Plo, MN, 0);
        reduce_k2<1><<<(MN / 4 + 255) / 256, 256, 0, stream>>>(
            PART + 4 * MN, MN, 4, W2_b, DSZ, nullptr, Phi + MN, Plo + MN, MN, 0);

        // U = P1@E2^T, V = P2@E1^T (+c)   split-K=4 -> 64 blk
        mfma_gemm<3, 0><<<dim3(1, 8, 8), 256, 0, stream>>>(
            Phi, Plo, EtHi, EtLo, PART, nullptr, nullptr, 0,
            DSZ, 4, NTP, NTP, MN, EN, 4 * UVN, UVN);
        uv_reduce<<<(UVN + 255) / 256, 256, 0, stream>>>(PART, CV, U, V, 4);

        // G[b] = P1_b @ P2_b^T   split-K=8 -> 64 blk, partials [b][s][128*128]
        mfma_gemm<3, 0><<<dim3(1, 1, 64), 256, 0, stream>>>(
            Phi, Plo, Phi + MN, Plo + MN, PART, nullptr, nullptr, 0,
            DSZ, 8, SS, SS, BSD, BSD, 8 * (long)SS * SS, (long)SS * SS);
        softmax_kernel<1><<<nBS, 128, 0, stream>>>(
            dep, PART, 8, (long)SS * SS, 7L * SS * SS, U, V, nullptr, AmHi, nullptr);

        // AGG = A @ h (batched, K=128), bf16 out fused -> 48 blk, no reduce
        mfma_gemm<1, 1><<<dim3(6, 1, 8), 256, 0, stream>>>(
            AmHi, nullptr, htHi, nullptr, nullptr, AGHi, nullptr, 0,
            SS, 1, HID, HID, (long)SS * SS, BSD, BSD, 0);

        // HSYN = relu(AGG @ gcn + b)   split-K=4 -> 192 blk
        mfma_gemm<1, 0><<<dim3(6, 8, 4), 256, 0, stream>>>(
            AGHi, nullptr, gTHi, nullptr, PART, nullptr, nullptr, 0,
            HID, 4, HID, HID, 0, 0, 0, MN);
        reduce_k2<2><<<(MN / 4 + 255) / 256, 256, 0, stream>>>(
            PART, MN, 4, gcn_b, HID, nullptr, HSHi, nullptr, MN, 1);

        // out = HSYN @ Wo + b   split-K=4 -> 192 blk
        mfma_gemm<1, 0><<<dim3(6, 8, 4), 256, 0, stream>>>(
            HSHi, nullptr, oTHi, nullptr, PART, nullptr, nullptr, 0,
            DSZ, 4, HID, HID, 0, 0, 0, MN);
        reduce_k2<0><<<(MN / 4 + 255) / 256, 256, 0, stream>>>(
            PART, MN, 4, Wo_b, HID, out, nullptr, nullptr, MN, 0);
    } else {
        // Fallback: verified fp32 nsplit=1 path, compact layout.
        float* ws = (float*)d_ws;
        long o2 = 0;
        float* Ef2  = ws + o2; o2 += 2 * EN;
        float* CV2  = ws + o2; o2 += 64;
        float* P1   = ws + o2; o2 += MN;
        float* P2   = ws + o2; o2 += MN;
        float* Uf   = ws + o2; o2 += UVN;
        float* Vf   = ws + o2; o2 += UVN;
        float* G    = ws + o2; o2 += BSS;
        float* Amat = ws + o2; o2 += BSS;
        float* AGG  = ws + o2; o2 += MN;
        float* HSYN = ws + o2; o2 += MN;
        unsigned short* Eh2 = (unsigned short*)(ws + o2); o2 += EN;
        unsigned short* El2 = (unsigned short*)(ws + o2); o2 += EN;

        e_kernel<<<(NTP * DSZ + 255) / 256, 256, 0, stream>>>(table, W1_w, W2_w, Ef2, Eh2, El2);
        c_kernel<<<NT, 256, 0, stream>>>(Ef2, CV2);
        gemm_k<<<dim3(DSZ / 64, nBS / 64, 1), 256, 0, stream>>>(
            h, W1_w, W1_b, P1, HID, 1, HID, DSZ, DSZ, 0, 0, 0, 0, 0);
        gemm_k<<<dim3(DSZ / 64, nBS / 64, 1), 256, 0, stream>>>(
            h, W2_w, W2_b, P2, HID, 1, HID, DSZ, DSZ, 0, 0, 0, 0, 0);
        uv_kernel<<<nBS, 256, 0, stream>>>(P1, P2, Ef2 + EN, Ef2, CV2, Uf, Vf);
        gram32<<<dim3(SS / 32, SS / 32, BB), 256, 0, stream>>>(P1, P2, G);
        softmax_kernel<0><<<nBS, 128, 0, stream>>>(dep, G, 1, BSS, 0, Uf, Vf, Amat, nullptr, nullptr);
        gemm_k<<<dim3(HID / 64, SS / 64, BB), 256, 0, stream>>>(
            Amat, h, nullptr, AGG, SS, 1, SS, HID, HID,
            (long)SS * SS, BSD, BSD, 0, 0);
        gemm_k<<<dim3(HID / 64, nBS / 64, 1), 256, 0, stream>>>(
            AGG, gcn_w, gcn_b, HSYN, HID, 1, HID, HID, HID, 0, 0, 0, 0, 1);
        gemm_k<<<dim3(HID / 64, nBS / 64, 1), 256, 0, stream>>>(
            HSYN, Wo_w, Wo_b, out, DSZ, 1, DSZ, HID, HID, 0, 0, 0, 0, 0);
    }
}

// Round 8
// 93.122 us; speedup vs baseline: 3.8124x; 1.1542x over previous
//
#include <hip/hip_runtime.h>
#include <hip/hip_bf16.h>

#define BB 8
#define SS 128
#define HID 768
#define DEP 64
#define DSZ 768
#define NT 45
#define NTP 48
#define NEG -1000000000.0f

typedef short bfv8 __attribute__((ext_vector_type(8)));
typedef float f32x4 __attribute__((ext_vector_type(4)));

__device__ __forceinline__ unsigned short f2bf(float x) {
    unsigned int u; __builtin_memcpy(&u, &x, 4);
    u += 0x7fffu + ((u >> 16) & 1u);
    return (unsigned short)(u >> 16);
}
__device__ __forceinline__ float bf2f(unsigned short h) {
    unsigned int u = ((unsigned int)h) << 16;
    float f; __builtin_memcpy(&f, &u, 4);
    return f;
}

// async global->LDS, 16B per lane. LDS dest is wave-uniform base;
// HW writes base + lane*16.
__device__ __forceinline__ void gld16(const unsigned short* gp, unsigned short* lp) {
    typedef __attribute__((address_space(1))) const unsigned int GU;
    typedef __attribute__((address_space(3))) unsigned int LU;
    __builtin_amdgcn_global_load_lds((GU*)(uintptr_t)gp,
                                     (LU*)(unsigned int)(uintptr_t)lp, 16, 0, 0);
}

// ---------------------------------------------------------------------------
// E: slot0 = E2 = table @ W2[HID:], slot1 = E1 = table @ W1[HID:].
__global__ void e_kernel(const float* __restrict__ table,
                         const float* __restrict__ W1,
                         const float* __restrict__ W2,
                         float* __restrict__ Ef,
                         unsigned short* __restrict__ Ehi,
                         unsigned short* __restrict__ Elo) {
    int idx = blockIdx.x * blockDim.x + threadIdx.x;
    if (idx >= NTP * DSZ) return;
    int t = idx / DSZ, e = idx % DSZ;
    float s1 = 0.f, s2 = 0.f;
    if (t < NT)
        for (int d = 0; d < DEP; ++d) {
            float td = table[t * DEP + d];
            s1 += td * W1[(HID + d) * DSZ + e];
            s2 += td * W2[(HID + d) * DSZ + e];
        }
    const long EN = (long)NTP * DSZ;
    Ef[idx] = s2; Ef[EN + idx] = s1;
    unsigned short h2 = f2bf(s2), h1 = f2bf(s1);
    Ehi[idx] = h2;      Elo[idx] = f2bf(s2 - bf2f(h2));
    Ehi[EN + idx] = h1; Elo[EN + idx] = f2bf(s1 - bf2f(h1));
}

// c[t] = dot(E1[t,:], E2[t,:])
__global__ void c_kernel(const float* __restrict__ Ef, float* __restrict__ cv) {
    int t = blockIdx.x;
    const long EN = (long)NTP * DSZ;
    float s = 0.f;
    for (int e = threadIdx.x; e < DSZ; e += 256)
        s += Ef[(long)t * DSZ + e] * Ef[EN + (long)t * DSZ + e];
    __shared__ float red[256];
    red[threadIdx.x] = s;
    __syncthreads();
    for (int w = 128; w >= 1; w >>= 1) {
        if (threadIdx.x < w) red[threadIdx.x] += red[threadIdx.x + w];
        __syncthreads();
    }
    if (threadIdx.x == 0) cv[t] = red[0];
}

// ---------------------------------------------------------------------------
// All conversions, one launch. Grid (24, 24, 12):
//   z<4:  weight which=z -> transposed hi (lo for W1/W2)
//   z>=4: h batch b=z-4 (y<4 only): straight hi/lo + transposed hi
__global__ __launch_bounds__(256) void conv_all(
    const float* __restrict__ h,
    const float* __restrict__ W1, const float* __restrict__ W2,
    const float* __restrict__ gcn, const float* __restrict__ Wo,
    unsigned short* __restrict__ hHi, unsigned short* __restrict__ hLo,
    unsigned short* __restrict__ htHi,
    unsigned short* __restrict__ WtHi, unsigned short* __restrict__ WtLo,
    unsigned short* __restrict__ gTHi, unsigned short* __restrict__ oTHi) {
    const long WN = (long)DSZ * HID;
    __shared__ float tile[32][33];
    int tr = threadIdx.x >> 5, tc = threadIdx.x & 31;
    int z = blockIdx.z;
    if (z < 4) {
        const float* src = z == 0 ? W1 : z == 1 ? W2 : z == 2 ? gcn : Wo;
        unsigned short* dhi = z == 0 ? WtHi : z == 1 ? WtHi + WN
                            : z == 2 ? gTHi : oTHi;
        unsigned short* dlo = z == 0 ? WtLo : z == 1 ? WtLo + WN : nullptr;
        int r0 = blockIdx.y * 32, c0 = blockIdx.x * 32;
#pragma unroll
        for (int k = 0; k < 4; ++k)
            tile[tr + k * 8][tc] = src[(long)(r0 + tr + k * 8) * 768 + c0 + tc];
        __syncthreads();
#pragma unroll
        for (int k = 0; k < 4; ++k) {
            int i = tr + k * 8, j = tc;
            float v = tile[j][i];
            unsigned short hh = f2bf(v);
            long o = (long)(c0 + i) * 768 + r0 + j;
            dhi[o] = hh;
            if (dlo) dlo[o] = f2bf(v - bf2f(hh));
        }
    } else {
        if (blockIdx.y >= SS / 32) return;
        int b = z - 4;
        int r0 = blockIdx.y * 32, c0 = blockIdx.x * 32;
        const float* Xb = h + (long)b * SS * HID;
#pragma unroll
        for (int k = 0; k < 4; ++k) {
            int rr = r0 + tr + k * 8, cc = c0 + tc;
            float v = Xb[(long)rr * HID + cc];
            tile[tr + k * 8][tc] = v;
            unsigned short hh = f2bf(v);
            long o = (long)b * SS * HID + (long)rr * HID + cc;
            hHi[o] = hh;
            hLo[o] = f2bf(v - bf2f(hh));
        }
        __syncthreads();
#pragma unroll
        for (int k = 0; k < 4; ++k) {
            int i = tr + k * 8, j = tc;
            float v = tile[j][i];
            long o = (long)b * (SS * HID) + (long)(c0 + i) * SS + (r0 + j);
            htHi[o] = f2bf(v);
        }
    }
}

// ---------------------------------------------------------------------------
// 128x128-tile MFMA GEMM (split-precision capable), fp32 partial out.
// PREC==3: D = Ahi*Bhi + Ahi*Blo + Alo*Bhi.  PREC==1: hi only.
template <int PREC>
__global__ __launch_bounds__(256) void mfma_gemm(
    const unsigned short* __restrict__ Ahi, const unsigned short* __restrict__ Alo,
    const unsigned short* __restrict__ Bhi, const unsigned short* __restrict__ Blo,
    float* __restrict__ C, int K, int nsplit, int ldc, int Nvalid,
    long sA, long sB, long sC, long splitStride) {
    int batch = blockIdx.z / nsplit, split = blockIdx.z - batch * nsplit;
    int kc = K / nsplit;
    int kb = split * kc;
    const unsigned short* ah = Ahi + (long)batch * sA;
    const unsigned short* bh = Bhi + (long)batch * sB;
    int m0 = blockIdx.y * 128, n0 = blockIdx.x * 128;

    __shared__ __align__(16) unsigned short sAh[4096], sBh[4096];
    __shared__ __align__(16) unsigned short sAl[PREC == 3 ? 4096 : 16];
    __shared__ __align__(16) unsigned short sBl[PREC == 3 ? 4096 : 16];
    int tid = threadIdx.x;
    int lane = tid & 63, wave = tid >> 6;
    int wr = wave >> 1, wc = wave & 1;
    int q = lane >> 4, r = lane & 15;

    f32x4 acc[4][4];
#pragma unroll
    for (int i = 0; i < 4; ++i)
#pragma unroll
        for (int j = 0; j < 4; ++j) acc[i][j] = (f32x4){0.f, 0.f, 0.f, 0.f};

    int s0 = tid, s1 = tid + 256;
    int arow0 = s0 >> 2, ak0 = (s0 & 3) << 3;
    int arow1 = s1 >> 2, ak1 = (s1 & 3) << 3;
    const unsigned short* aP0 = ah + (long)(m0 + arow0) * K + ak0;
    const unsigned short* aP1 = ah + (long)(m0 + arow1) * K + ak1;
    bool bok0 = (n0 + arow0) < Nvalid, bok1 = (n0 + arow1) < Nvalid;
    const unsigned short* bP0 = bh + (long)(n0 + arow0) * K + ak0;
    const unsigned short* bP1 = bh + (long)(n0 + arow1) * K + ak1;
    const unsigned short* alP0 = nullptr; const unsigned short* alP1 = nullptr;
    const unsigned short* blP0 = nullptr; const unsigned short* blP1 = nullptr;
    if constexpr (PREC == 3) {
        const unsigned short* al = Alo + (long)batch * sA;
        const unsigned short* bl = Blo + (long)batch * sB;
        alP0 = al + (long)(m0 + arow0) * K + ak0;
        alP1 = al + (long)(m0 + arow1) * K + ak1;
        blP0 = bl + (long)(n0 + arow0) * K + ak0;
        blP1 = bl + (long)(n0 + arow1) * K + ak1;
    }
    unsigned short* lA0 = sAh + (wave << 9);
    unsigned short* lA1 = sAh + 2048 + (wave << 9);
    unsigned short* lB0 = sBh + (wave << 9);
    unsigned short* lB1 = sBh + 2048 + (wave << 9);
    unsigned short* lAl0 = sAl + (wave << 9);
    unsigned short* lAl1 = sAl + 2048 + (wave << 9);
    unsigned short* lBl0 = sBl + (wave << 9);
    unsigned short* lBl1 = sBl + 2048 + (wave << 9);

    int aOff[4], bOff[4];
#pragma unroll
    for (int f = 0; f < 4; ++f) {
        aOff[f] = (wr * 64 + f * 16 + r) * 32 + q * 8;
        bOff[f] = (wc * 64 + f * 16 + r) * 32 + q * 8;
    }

    for (int k0 = kb; k0 < kb + kc; k0 += 32) {
        __syncthreads();
        gld16(aP0 + k0, lA0);
        gld16(aP1 + k0, lA1);
        if (bok0) gld16(bP0 + k0, lB0);
        if (bok1) gld16(bP1 + k0, lB1);
        if constexpr (PREC == 3) {
            gld16(alP0 + k0, lAl0);
            gld16(alP1 + k0, lAl1);
            if (bok0) gld16(blP0 + k0, lBl0);
            if (bok1) gld16(blP1 + k0, lBl1);
        }
        __syncthreads();

        bfv8 bh_r[4], bl_r[4];
#pragma unroll
        for (int fc = 0; fc < 4; ++fc) {
            bh_r[fc] = *(const bfv8*)(sBh + bOff[fc]);
            if constexpr (PREC == 3) bl_r[fc] = *(const bfv8*)(sBl + bOff[fc]);
        }
#pragma unroll
        for (int fr = 0; fr < 4; ++fr) {
            bfv8 a_h = *(const bfv8*)(sAh + aOff[fr]);
            bfv8 a_l;
            if constexpr (PREC == 3) a_l = *(const bfv8*)(sAl + aOff[fr]);
#pragma unroll
            for (int fc = 0; fc < 4; ++fc) {
                acc[fr][fc] = __builtin_amdgcn_mfma_f32_16x16x32_bf16(a_h, bh_r[fc], acc[fr][fc], 0, 0, 0);
                if constexpr (PREC == 3) {
                    acc[fr][fc] = __builtin_amdgcn_mfma_f32_16x16x32_bf16(a_h, bl_r[fc], acc[fr][fc], 0, 0, 0);
                    acc[fr][fc] = __builtin_amdgcn_mfma_f32_16x16x32_bf16(a_l, bh_r[fc], acc[fr][fc], 0, 0, 0);
                }
            }
        }
    }
    float* Cb = C + (long)batch * sC + (long)split * splitStride;
#pragma unroll
    for (int fr = 0; fr < 4; ++fr) {
        int rr = m0 + wr * 64 + fr * 16 + q * 4;
#pragma unroll
        for (int fc = 0; fc < 4; ++fc) {
            int cc = n0 + wc * 64 + fc * 16 + r;
            if (cc < Nvalid) {
#pragma unroll
                for (int i = 0; i < 4; ++i)
                    Cb[(long)(rr + i) * ldc + cc] = acc[fr][fc][i];
            }
        }
    }
}

// ---------------------------------------------------------------------------
// 64x64-tile bf16 GEMM, no split-K, fused epilogue.
// OUT==1: bf16 out (+bias)(+relu).  OUT==2: fp32 out (+bias).
// 256 thr = 4 waves (2x2), 2x2 frags/wave. BK=32, K-loop len K/32.
template <int OUT>
__global__ __launch_bounds__(256) void gemm64(
    const unsigned short* __restrict__ Ahi, const unsigned short* __restrict__ Bhi,
    const float* __restrict__ bias, unsigned short* __restrict__ Cb16,
    float* __restrict__ Cf, int relu, int K, int ldc,
    long sA, long sB, long sC) {
    int batch = blockIdx.z;
    int m0 = blockIdx.y * 64, n0 = blockIdx.x * 64;
    const unsigned short* ah = Ahi + (long)batch * sA;
    const unsigned short* bh = Bhi + (long)batch * sB;

    __shared__ __align__(16) unsigned short sAh[2048], sBh[2048];
    int tid = threadIdx.x;
    int lane = tid & 63, wave = tid >> 6;
    int wr = wave >> 1, wc = wave & 1;
    int q = lane >> 4, r = lane & 15;

    f32x4 acc[2][2];
#pragma unroll
    for (int i = 0; i < 2; ++i)
#pragma unroll
        for (int j = 0; j < 2; ++j) acc[i][j] = (f32x4){0.f, 0.f, 0.f, 0.f};

    // seg s = tid: row = s>>2 (64 rows), kseg = s&3 (8 shorts each)
    int arow = tid >> 2, ak = (tid & 3) << 3;
    const unsigned short* aP = ah + (long)(m0 + arow) * K + ak;
    const unsigned short* bP = bh + (long)(n0 + arow) * K + ak;
    unsigned short* lA = sAh + (wave << 9);  // 512 shorts/wave
    unsigned short* lB = sBh + (wave << 9);

    int aOff[2], bOff[2];
#pragma unroll
    for (int f = 0; f < 2; ++f) {
        aOff[f] = (wr * 32 + f * 16 + r) * 32 + q * 8;
        bOff[f] = (wc * 32 + f * 16 + r) * 32 + q * 8;
    }

    for (int k0 = 0; k0 < K; k0 += 32) {
        __syncthreads();
        gld16(aP + k0, lA);
        gld16(bP + k0, lB);
        __syncthreads();
        bfv8 b0 = *(const bfv8*)(sBh + bOff[0]);
        bfv8 b1 = *(const bfv8*)(sBh + bOff[1]);
#pragma unroll
        for (int fr = 0; fr < 2; ++fr) {
            bfv8 a = *(const bfv8*)(sAh + aOff[fr]);
            acc[fr][0] = __builtin_amdgcn_mfma_f32_16x16x32_bf16(a, b0, acc[fr][0], 0, 0, 0);
            acc[fr][1] = __builtin_amdgcn_mfma_f32_16x16x32_bf16(a, b1, acc[fr][1], 0, 0, 0);
        }
    }
#pragma unroll
    for (int fr = 0; fr < 2; ++fr) {
        int rr = m0 + wr * 32 + fr * 16 + q * 4;
#pragma unroll
        for (int fc = 0; fc < 2; ++fc) {
            int cc = n0 + wc * 32 + fc * 16 + r;
            float bv = bias ? bias[cc] : 0.f;
#pragma unroll
            for (int i = 0; i < 4; ++i) {
                float v = acc[fr][fc][i] + bv;
                if (OUT == 1) {
                    if (relu) v = fmaxf(v, 0.f);
                    Cb16[(long)batch * sC + (long)(rr + i) * ldc + cc] = f2bf(v);
                } else {
                    Cf[(long)batch * sC + (long)(rr + i) * ldc + cc] = v;
                }
            }
        }
    }
}

// ---------------------------------------------------------------------------
// P1/P2 merged split-K reduce: part holds [2 which][4 split][MN] fp32.
__global__ __launch_bounds__(256) void reduce_P(
    const float* __restrict__ part, const float* __restrict__ b1,
    const float* __restrict__ b2, unsigned short* __restrict__ Phi,
    unsigned short* __restrict__ Plo) {
    const long MN = (long)BB * SS * DSZ;
    const long qn = MN / 4;
    long i = (long)blockIdx.x * 256 + threadIdx.x;
    if (i >= 2 * qn) return;
    int which = i >= qn;
    long ii = i - (long)which * qn;
    const float* p = part + (long)which * 4 * MN;
    float4 s = ((const float4*)p)[ii];
#pragma unroll
    for (int sp = 1; sp < 4; ++sp) {
        float4 t = ((const float4*)(p + (long)sp * MN))[ii];
        s.x += t.x; s.y += t.y; s.z += t.z; s.w += t.w;
    }
    const float* bias = which ? b2 : b1;
    long col = (ii * 4) % DSZ;
    s.x += bias[col]; s.y += bias[col + 1];
    s.z += bias[col + 2]; s.w += bias[col + 3];
    ushort4 h, l;
    h.x = f2bf(s.x); l.x = f2bf(s.x - bf2f(h.x));
    h.y = f2bf(s.y); l.y = f2bf(s.y - bf2f(h.y));
    h.z = f2bf(s.z); l.z = f2bf(s.z - bf2f(h.z));
    h.w = f2bf(s.w); l.w = f2bf(s.w - bf2f(h.w));
    ((ushort4*)Phi)[i] = h;
    ((ushort4*)Plo)[i] = l;
}

// U/V partial reduce: Up z-order = which(U=0,V=1)*nsplit + split, each 1024*48.
__global__ __launch_bounds__(256) void uv_reduce(
    const float* __restrict__ Up, const float* __restrict__ cv,
    float* __restrict__ U, float* __restrict__ V, int nsplit) {
    const long n = (long)BB * SS * NTP;
    long idx = (long)blockIdx.x * 256 + threadIdx.x;
    if (idx >= n) return;
    int t = idx % NTP;
    float su = 0.f, sv = 0.f;
    for (int s = 0; s < nsplit; ++s) {
        su += Up[(long)s * n + idx];
        sv += Up[((long)nsplit + s) * n + idx];
    }
    U[idx] = su;
    V[idx] = sv + (t < NT ? cv[t] : 0.f);
}

// ---------------------------------------------------------------------------
// relevance (sum split partials of G) + mask + softmax over j.
template <int HILO>
__global__ __launch_bounds__(128) void softmax_kernel(
    const int* __restrict__ dep, const float* __restrict__ Gp, int nsplit,
    long splitStride, long batchExtra,
    const float* __restrict__ U, const float* __restrict__ V,
    float* __restrict__ Af, unsigned short* __restrict__ Ahi,
    unsigned short* __restrict__ Alo) {
    int bi = blockIdx.x;
    int b = bi >> 7;
    int j = threadIdx.x;
    int t = dep[(long)bi * SS + j];
    float r;
    if (t != 0) {
        long gbase = (long)bi * SS + j + (long)b * batchExtra;
        float g = 0.f;
        for (int s = 0; s < nsplit; ++s) g += Gp[gbase + (long)s * splitStride];
        r = g + U[(long)bi * NTP + t] + V[((long)b * SS + j) * NTP + t];
    } else {
        r = NEG;
    }
    float m = r;
    for (int off = 1; off < 64; off <<= 1) m = fmaxf(m, __shfl_xor(m, off));
    __shared__ float smax[2], ssum[2];
    if ((threadIdx.x & 63) == 0) smax[threadIdx.x >> 6] = m;
    __syncthreads();
    m = fmaxf(smax[0], smax[1]);
    float p = expf(r - m);
    float s = p;
    for (int off = 1; off < 64; off <<= 1) s += __shfl_xor(s, off);
    if ((threadIdx.x & 63) == 0) ssum[threadIdx.x >> 6] = s;
    __syncthreads();
    s = ssum[0] + ssum[1];
    float v = p / s;
    if (HILO) {
        Ahi[(long)bi * SS + j] = f2bf(v);
    } else {
        Af[(long)bi * SS + j] = v;
    }
}

// ===========================================================================
// Legacy fp32 path (ws-size fallback) — verified in rounds 1-3.
__device__ __forceinline__ void gemm_body(
    const float* __restrict__ Ab, const float* __restrict__ Bb,
    const float* __restrict__ bias, float* __restrict__ Cb,
    int kbeg, int kend, int lda, int ldb, int ldc,
    int row0, int col0, bool relu) {
    __shared__ float As[16][68];
    __shared__ float Bs[16][68];
    int tx = threadIdx.x & 15, ty = threadIdx.x >> 4;
    float acc[4][4] = {};
    for (int k0 = kbeg; k0 < kend; k0 += 16) {
#pragma unroll
        for (int l = 0; l < 4; ++l) {
            int idx = threadIdx.x + l * 256;
            int r = idx >> 4, kk = idx & 15;
            As[kk][r] = Ab[(long)(row0 + r) * lda + k0 + kk];
            int kk2 = idx >> 6, cc = idx & 63;
            Bs[kk2][cc] = Bb[(long)(k0 + kk2) * ldb + col0 + cc];
        }
        __syncthreads();
#pragma unroll
        for (int kk = 0; kk < 16; ++kk) {
            float4 a4 = *(const float4*)&As[kk][ty * 4];
            float4 b4 = *(const float4*)&Bs[kk][tx * 4];
            float a[4] = {a4.x, a4.y, a4.z, a4.w};
            float b[4] = {b4.x, b4.y, b4.z, b4.w};
#pragma unroll
            for (int i = 0; i < 4; ++i)
#pragma unroll
                for (int j = 0; j < 4; ++j) acc[i][j] += a[i] * b[j];
        }
        __syncthreads();
    }
#pragma unroll
    for (int i = 0; i < 4; ++i) {
        int r = row0 + ty * 4 + i;
#pragma unroll
        for (int j = 0; j < 4; ++j) {
            int c = col0 + tx * 4 + j;
            float v = acc[i][j];
            if (bias) v += bias[c];
            if (relu) v = fmaxf(v, 0.f);
            Cb[(long)r * ldc + c] = v;
        }
    }
}

__global__ __launch_bounds__(256) void gemm_k(
    const float* __restrict__ A, const float* __restrict__ B,
    const float* __restrict__ bias, float* __restrict__ C,
    int K, int nsplit, int lda, int ldb, int ldc,
    long sA, long sB, long sC, long splitStride, int relu) {
    int batch = blockIdx.z / nsplit, split = blockIdx.z % nsplit;
    int kc = K / nsplit;
    const float* Ab = A + (long)batch * sA;
    const float* Bb = B + (long)batch * sB;
    float* Cb = C + (long)batch * sC + (long)split * splitStride;
    gemm_body(Ab, Bb, nsplit == 1 ? bias : nullptr, Cb,
              split * kc, split * kc + kc, lda, ldb, ldc,
              blockIdx.y * 64, blockIdx.x * 64, relu && nsplit == 1);
}

__global__ __launch_bounds__(256) void gram32(
    const float* __restrict__ P1, const float* __restrict__ P2,
    float* __restrict__ Gp) {
    int b = blockIdx.z;
    int i0 = blockIdx.y * 32, j0 = blockIdx.x * 32;
    __shared__ float As[32][33];
    __shared__ float Bs[32][33];
    const float* p1 = P1 + (long)b * SS * DSZ;
    const float* p2 = P2 + (long)b * SS * DSZ;
    int tx = threadIdx.x % 32, ty = threadIdx.x / 32;
    float acc[4] = {0.f, 0.f, 0.f, 0.f};
    for (int k0 = 0; k0 < DSZ; k0 += 32) {
#pragma unroll
        for (int l = 0; l < 4; ++l) {
            int idx = threadIdx.x + l * 256;
            int r = idx / 32, kk = idx % 32;
            As[kk][r] = p1[(long)(i0 + r) * DSZ + k0 + kk];
            Bs[kk][r] = p2[(long)(j0 + r) * DSZ + k0 + kk];
        }
        __syncthreads();
#pragma unroll
        for (int kk = 0; kk < 32; ++kk) {
            float bv = Bs[kk][tx];
#pragma unroll
            for (int i = 0; i < 4; ++i) acc[i] += As[kk][ty * 4 + i] * bv;
        }
        __syncthreads();
    }
#pragma unroll
    for (int i = 0; i < 4; ++i)
        Gp[((long)b * SS + i0 + ty * 4 + i) * SS + j0 + tx] = acc[i];
}

__global__ __launch_bounds__(256) void uv_kernel(
    const float* __restrict__ P1, const float* __restrict__ P2,
    const float* __restrict__ E1, const float* __restrict__ E2,
    const float* __restrict__ cv, float* __restrict__ U, float* __restrict__ V) {
    int bs = blockIdx.x;
    __shared__ float p1[DSZ], p2[DSZ];
    for (int e = threadIdx.x; e < DSZ; e += 256) {
        p1[e] = P1[(long)bs * DSZ + e];
        p2[e] = P2[(long)bs * DSZ + e];
    }
    __syncthreads();
    int wave = threadIdx.x / 64, lane = threadIdx.x % 64;
    for (int t = wave; t < NT; t += 4) {
        float su = 0.f, sv = 0.f;
        for (int e = lane; e < DSZ; e += 64) {
            su += p1[e] * E2[(long)t * DSZ + e];
            sv += p2[e] * E1[(long)t * DSZ + e];
        }
        for (int off = 32; off >= 1; off >>= 1) {
            su += __shfl_down(su, off);
            sv += __shfl_down(sv, off);
        }
        if (lane == 0) {
            U[(long)bs * NTP + t] = su;
            V[(long)bs * NTP + t] = sv + cv[t];
        }
    }
}

// ---------------------------------------------------------------------------
extern "C" void kernel_launch(void* const* d_in, const int* in_sizes, int n_in,
                              void* d_out, int out_size, void* d_ws, size_t ws_size,
                              hipStream_t stream) {
    const float* h      = (const float*)d_in[0];
    const int*   dep    = (const int*)d_in[1];
    const float* table  = (const float*)d_in[2];
    const float* W1_w   = (const float*)d_in[3];
    const float* W1_b   = (const float*)d_in[4];
    const float* W2_w   = (const float*)d_in[5];
    const float* W2_b   = (const float*)d_in[6];
    const float* gcn_w  = (const float*)d_in[7];
    const float* gcn_b  = (const float*)d_in[8];
    const float* Wo_w   = (const float*)d_in[9];
    const float* Wo_b   = (const float*)d_in[10];
    float* out = (float*)d_out;

    const long nBS = (long)BB * SS;        // 1024
    const long MN  = nBS * DSZ;            // 786432
    const long BSS = (long)BB * SS * SS;   // 131072
    const long UVN = nBS * NTP;            // 49152
    const long EN  = (long)NTP * DSZ;      // 36864
    const long WN  = (long)DSZ * HID;      // 589824
    const long BSD = (long)SS * DSZ;       // 98304

    char* base = (char*)d_ws;
    size_t off = 0;
    auto alloc = [&](size_t bytes) -> void* {
        void* p = base + off;
        off += (bytes + 255) & ~(size_t)255;
        return p;
    };

    float* Ef    = (float*)alloc(2 * EN * 4);
    float* CV    = (float*)alloc(256);
    float* U     = (float*)alloc(UVN * 4);
    float* V     = (float*)alloc(UVN * 4);
    float* PART  = (float*)alloc(8 * MN * 4);
    unsigned short* EtHi = (unsigned short*)alloc(2 * EN * 2);
    unsigned short* EtLo = (unsigned short*)alloc(2 * EN * 2);
    unsigned short* hHi  = (unsigned short*)alloc(MN * 2);
    unsigned short* hLo  = (unsigned short*)alloc(MN * 2);
    unsigned short* htHi = (unsigned short*)alloc(MN * 2);
    unsigned short* WtHi = (unsigned short*)alloc(2 * WN * 2);
    unsigned short* WtLo = (unsigned short*)alloc(2 * WN * 2);
    unsigned short* gTHi = (unsigned short*)alloc(WN * 2);
    unsigned short* oTHi = (unsigned short*)alloc(WN * 2);
    unsigned short* Phi  = (unsigned short*)alloc(2 * MN * 2);
    unsigned short* Plo  = (unsigned short*)alloc(2 * MN * 2);
    unsigned short* AmHi = (unsigned short*)alloc(BSS * 2);
    unsigned short* AGHi = (unsigned short*)alloc(MN * 2);
    unsigned short* HSHi = (unsigned short*)alloc(MN * 2);
    size_t needBig = off;

    if (ws_size >= needBig) {
        e_kernel<<<(NTP * DSZ + 255) / 256, 256, 0, stream>>>(table, W1_w, W2_w, Ef, EtHi, EtLo);
        c_kernel<<<NT, 256, 0, stream>>>(Ef, CV);

        // all conversions, one launch
        conv_all<<<dim3(24, 24, 12), 256, 0, stream>>>(
            h, W1_w, W2_w, gcn_w, Wo_w, hHi, hLo, htHi, WtHi, WtLo, gTHi, oTHi);

        // P1/P2 = h @ {W1,W2}[:HID] + b   (dual via batch, split-K=4 -> 384 blk)
        mfma_gemm<3><<<dim3(6, 8, 8), 256, 0, stream>>>(
            hHi, hLo, WtHi, WtLo, PART, HID, 4, DSZ, DSZ, 0, WN, 4 * MN, MN);
        reduce_P<<<(2 * MN / 4 + 255) / 256, 256, 0, stream>>>(
            PART, W1_b, W2_b, Phi, Plo);

        // U = P1@E2^T, V = P2@E1^T (+c)   split-K=4 -> 64 blk
        mfma_gemm<3><<<dim3(1, 8, 8), 256, 0, stream>>>(
            Phi, Plo, EtHi, EtLo, PART, DSZ, 4, NTP, NTP, MN, EN, 4 * UVN, UVN);
        uv_reduce<<<(UVN + 255) / 256, 256, 0, stream>>>(PART, CV, U, V, 4);

        // G[b] = P1_b @ P2_b^T   split-K=8 -> 64 blk
        mfma_gemm<3><<<dim3(1, 1, 64), 256, 0, stream>>>(
            Phi, Plo, Phi + MN, Plo + MN, PART, DSZ, 8, SS, SS, BSD, BSD,
            8 * (long)SS * SS, (long)SS * SS);
        softmax_kernel<1><<<nBS, 128, 0, stream>>>(
            dep, PART, 8, (long)SS * SS, 7L * SS * SS, U, V, nullptr, AmHi, nullptr);

        // AGG = A @ h (batched, K=128), 64-tile -> 192 blk, bf16 fused
        gemm64<1><<<dim3(12, 2, 8), 256, 0, stream>>>(
            AmHi, htHi, nullptr, AGHi, nullptr, 0, SS, HID,
            (long)SS * SS, BSD, BSD);

        // HSYN = relu(AGG @ gcn + b)   64-tile, no split -> 192 blk
        gemm64<1><<<dim3(12, 16, 1), 256, 0, stream>>>(
            AGHi, gTHi, gcn_b, HSHi, nullptr, 1, HID, HID, 0, 0, 0);

        // out = HSYN @ Wo + b   64-tile, fp32 direct -> 192 blk
        gemm64<2><<<dim3(12, 16, 1), 256, 0, stream>>>(
            HSHi, oTHi, Wo_b, nullptr, out, 0, DSZ, HID, 0, 0, 0);
    } else {
        // Fallback: verified fp32 nsplit=1 path, compact layout.
        float* ws = (float*)d_ws;
        long o2 = 0;
        float* Ef2  = ws + o2; o2 += 2 * EN;
        float* CV2  = ws + o2; o2 += 64;
        float* P1   = ws + o2; o2 += MN;
        float* P2   = ws + o2; o2 += MN;
        float* Uf   = ws + o2; o2 += UVN;
        float* Vf   = ws + o2; o2 += UVN;
        float* G    = ws + o2; o2 += BSS;
        float* Amat = ws + o2; o2 += BSS;
        float* AGG  = ws + o2; o2 += MN;
        float* HSYN = ws + o2; o2 += MN;
        unsigned short* Eh2 = (unsigned short*)(ws + o2); o2 += EN;
        unsigned short* El2 = (unsigned short*)(ws + o2); o2 += EN;

        e_kernel<<<(NTP * DSZ + 255) / 256, 256, 0, stream>>>(table, W1_w, W2_w, Ef2, Eh2, El2);
        c_kernel<<<NT, 256, 0, stream>>>(Ef2, CV2);
        gemm_k<<<dim3(DSZ / 64, nBS / 64, 1), 256, 0, stream>>>(
            h, W1_w, W1_b, P1, HID, 1, HID, DSZ, DSZ, 0, 0, 0, 0, 0);
        gemm_k<<<dim3(DSZ / 64, nBS / 64, 1), 256, 0, stream>>>(
            h, W2_w, W2_b, P2, HID, 1, HID, DSZ, DSZ, 0, 0, 0, 0, 0);
        uv_kernel<<<nBS, 256, 0, stream>>>(P1, P2, Ef2 + EN, Ef2, CV2, Uf, Vf);
        gram32<<<dim3(SS / 32, SS / 32, BB), 256, 0, stream>>>(P1, P2, G);
        softmax_kernel<0><<<nBS, 128, 0, stream>>>(dep, G, 1, BSS, 0, Uf, Vf, Amat, nullptr, nullptr);
        gemm_k<<<dim3(HID / 64, SS / 64, BB), 256, 0, stream>>>(
            Amat, h, nullptr, AGG, SS, 1, SS, HID, HID,
            (long)SS * SS, BSD, BSD, 0, 0);
        gemm_k<<<dim3(HID / 64, nBS / 64, 1), 256, 0, stream>>>(
            AGG, gcn_w, gcn_b, HSYN, HID, 1, HID, HID, HID, 0, 0, 0, 0, 1);
        gemm_k<<<dim3(HID / 64, nBS / 64, 1), 256, 0, stream>>>(
            HSYN, Wo_w, Wo_b, out, DSZ, 1, DSZ, HID, HID, 0, 0, 0, 0, 0);
    }
}